// Round 6
// baseline (560.833 us; speedup 1.0000x reference)
//
#include <hip/hip_runtime.h>
#include <hip/hip_bf16.h>

typedef __hip_bfloat16 bf16;

#define B_GR 8
#define IN_CH 64
#define H1 68
#define H2 128
#define ATTN 32
#define E4 512
#define RNN 128
#define KNN 16
#define EPSV 1e-5f

typedef __attribute__((ext_vector_type(8))) short s8v;
typedef __attribute__((ext_vector_type(4))) float f4v;
#define MFMA16(a,b,c) __builtin_amdgcn_mfma_f32_16x16x32_bf16(a,b,c,0,0,0)

// strides (elements) — +8 pad keeps 16B alignment, breaks pow2 banks
#define SK96 104
#define SK128 136
#define SK512 520

template<int DT> __device__ __forceinline__ float LD(const void* p, size_t i) {
    if (DT) return __bfloat162float(((const bf16*)p)[i]);
    return ((const float*)p)[i];
}
template<int DT> __device__ __forceinline__ void ST(void* p, size_t i, float v) {
    if (DT) ((bf16*)p)[i] = __float2bfloat16(v);
    else    ((float*)p)[i] = v;
}
__device__ __forceinline__ unsigned short f2bfb(float f) {
    unsigned u = __float_as_uint(f);
    unsigned r = (u + 0x7FFFu + ((u >> 16) & 1u)) >> 16;
    return (unsigned short)r;
}
__device__ __forceinline__ float bfb2f(unsigned short u) {
    return __uint_as_float(((unsigned)u) << 16);
}

// ---------------- prep: dtype detect + zero pooled ----------------
__global__ void prep_kernel(const void* pos, int* flag, int* pooled) {
    const int tid = threadIdx.x;
    for (int i = tid; i < B_GR*H1; i += 256) pooled[i] = 0;
    if (tid == 0) {
        const unsigned* w = (const unsigned*)pos;
        int ok = 1;
        #pragma unroll 8
        for (int i = 0; i < 256; i++) {
            float f = __uint_as_float((w[i] & 0xFFFFu) << 16);
            if (!(f >= -0.01f && f <= 10.05f)) ok = 0;
        }
        *flag = ok;
    }
}

// ---------------- transpose+convert weights into ws (bf16 bits) ----------------
#define W1T_E (128*SK96)
#define W2T_E (128*SK128)
#define AW1T_E (32*SK128)
#define EXPT_E (512*SK128)
#define D1T_E (512*SK512)
#define D2T_E (512*SK512)
#define PJT_E (128*SK512)
#define GW2T_E (80*SK96)
template<int DT> __global__ __launch_bounds__(256) void trans_kernel(
    const int* __restrict__ flag,
    const void* __restrict__ w1, const void* __restrict__ w2, const void* __restrict__ aw1,
    const void* __restrict__ expw, const void* __restrict__ d1pw,
    const void* __restrict__ d2pw, const void* __restrict__ pjw,
    const void* __restrict__ gw2,
    unsigned short* __restrict__ w1T, unsigned short* __restrict__ w2T,
    unsigned short* __restrict__ aw1T, unsigned short* __restrict__ expwT,
    unsigned short* __restrict__ d1pwT, unsigned short* __restrict__ d2pwT,
    unsigned short* __restrict__ pjwT, unsigned short* __restrict__ gw2gT)
{
    if (*flag != DT) return;
    const int T0 = W1T_E, T1 = T0+W2T_E, T2 = T1+AW1T_E, T3 = T2+EXPT_E,
              T4 = T3+D1T_E, T5 = T4+D2T_E, T6 = T5+PJT_E, T7 = T6+GW2T_E;
    for (int i = blockIdx.x*256 + threadIdx.x; i < T7; i += gridDim.x*256) {
        if (i < T0) {
            int n = i / SK96, k = i - n*SK96;
            w1T[i] = (k < H1) ? f2bfb(LD<DT>(w1, (size_t)k*H2 + n)) : 0;
        } else if (i < T1) {
            int j = i - T0; int n = j / SK128, k = j - n*SK128;
            w2T[j] = (k < H2) ? f2bfb(LD<DT>(w2, (size_t)k*H2 + n)) : 0;
        } else if (i < T2) {
            int j = i - T1; int n = j / SK128, k = j - n*SK128;
            aw1T[j] = (k < H2) ? f2bfb(LD<DT>(aw1, (size_t)k*ATTN + n)) : 0;
        } else if (i < T3) {
            int j = i - T2; int n = j / SK128, k = j - n*SK128;
            expwT[j] = (k < RNN) ? f2bfb(LD<DT>(expw, (size_t)k*E4 + n)) : 0;
        } else if (i < T4) {
            int j = i - T3; int n = j / SK512, k = j - n*SK512;
            d1pwT[j] = (k < E4) ? f2bfb(LD<DT>(d1pw, (size_t)k*E4 + n)) : 0;
        } else if (i < T5) {
            int j = i - T4; int n = j / SK512, k = j - n*SK512;
            d2pwT[j] = (k < E4) ? f2bfb(LD<DT>(d2pw, (size_t)k*E4 + n)) : 0;
        } else if (i < T6) {
            int j = i - T5; int n = j / SK512, k = j - n*SK512;
            pjwT[j] = (k < E4) ? f2bfb(LD<DT>(pjw, (size_t)k*RNN + n)) : 0;
        } else {
            int j = i - T6; int n = j / SK96, k = j - n*SK96;
            gw2gT[j] = (k < H1 && n < H1) ? f2bfb(LD<DT>(gw2, (size_t)k*H1 + n)) : 0;
        }
    }
}

// ---------------- folded per-column affine coefficients for post ----------------
template<int DT> __global__ void coef_kernel(
    const int* __restrict__ flag,
    const void* __restrict__ expb, const void* __restrict__ expbn,
    const void* __restrict__ d1dw, const void* __restrict__ d1bn1,
    const void* __restrict__ d1pb, const void* __restrict__ d1bn2, const void* __restrict__ bbn1,
    const void* __restrict__ d2dw, const void* __restrict__ d2bn1,
    const void* __restrict__ d2pb, const void* __restrict__ d2bn2, const void* __restrict__ bbn2,
    const void* __restrict__ pjb, const void* __restrict__ pjbn,
    float4* __restrict__ C1, float2* __restrict__ C2, float2* __restrict__ C3,
    float2* __restrict__ C4)
{
    if (*flag != DT) return;
    int c = blockIdx.x*256 + threadIdx.x;
    if (c < E4) {
        float a_e = LD<DT>(expbn,c) * rsqrtf(LD<DT>(expbn,3*E4+c)+EPSV);
        float t0  = a_e*(LD<DT>(expb,c) - LD<DT>(expbn,2*E4+c)) + LD<DT>(expbn,E4+c);
        float a1 = LD<DT>(d1bn1,c) * rsqrtf(LD<DT>(d1bn1,3*E4+c)+EPSV);
        float s1 = a1 * LD<DT>(d1dw,c);
        float t1 = a1*(LD<DT>(d1dw,E4+c) - LD<DT>(d1bn1,2*E4+c)) + LD<DT>(d1bn1,E4+c);
        C1[c] = make_float4(a_e, t0, s1, t1);
        float a2 = LD<DT>(d1bn2,c) * rsqrtf(LD<DT>(d1bn2,3*E4+c)+EPSV);
        float t2 = a2*(LD<DT>(d1pb,c) - LD<DT>(d1bn2,2*E4+c)) + LD<DT>(d1bn2,E4+c);
        float a3 = LD<DT>(bbn1,c) * rsqrtf(LD<DT>(bbn1,3*E4+c)+EPSV);
        float S2 = a3*a2;
        float T2 = a3*(t2 - LD<DT>(bbn1,2*E4+c)) + LD<DT>(bbn1,E4+c);
        float a4 = LD<DT>(d2bn1,c) * rsqrtf(LD<DT>(d2bn1,3*E4+c)+EPSV);
        float sdw = a4 * LD<DT>(d2dw,c);
        float tdw = a4*(LD<DT>(d2dw,E4+c) - LD<DT>(d2bn1,2*E4+c)) + LD<DT>(d2bn1,E4+c);
        C2[c] = make_float2(sdw*S2, sdw*T2 + tdw);
        float a5 = LD<DT>(d2bn2,c) * rsqrtf(LD<DT>(d2bn2,3*E4+c)+EPSV);
        float t5 = a5*(LD<DT>(d2pb,c) - LD<DT>(d2bn2,2*E4+c)) + LD<DT>(d2bn2,E4+c);
        float a6 = LD<DT>(bbn2,c) * rsqrtf(LD<DT>(bbn2,3*E4+c)+EPSV);
        C3[c] = make_float2(a6*a5, a6*(t5 - LD<DT>(bbn2,2*E4+c)) + LD<DT>(bbn2,E4+c));
    }
    if (c < RNN) {
        float ap = LD<DT>(pjbn,c) * rsqrtf(LD<DT>(pjbn,3*RNN+c)+EPSV);
        C4[c] = make_float2(ap, ap*(LD<DT>(pjb,c) - LD<DT>(pjbn,2*RNN+c)) + LD<DT>(pjbn,RNN+c));
    }
}

// ---------------- gate: layer1 VALU + layer2 MFMA + segment max ----------------
template<int DT> __global__ __launch_bounds__(256) void gate_mfma(
    const int* __restrict__ flag,
    const void* __restrict__ pos, const void* __restrict__ refl,
    const void* __restrict__ w1, const void* __restrict__ b1, const void* __restrict__ b2g,
    const unsigned short* __restrict__ gw2gT,
    int* __restrict__ pooled, int NPC, int CPB)
{
    if (*flag != DT) return;
    __shared__ __align__(16) unsigned short hs[256*SK96];
    __shared__ float w1s[4*H1], b1s[H1], b2s[H1];
    const int tid = threadIdx.x;
    for (int i = tid; i < 4*H1; i += 256) w1s[i] = LD<DT>(w1, i);
    if (tid < H1) { b1s[tid] = LD<DT>(b1, tid); b2s[tid] = LD<DT>(b2g, tid); }
    __syncthreads();

    const int bb = blockIdx.x / CPB;
    const int cc = blockIdx.x % CPB;
    const int base = bb*NPC + cc*256;
    const int limit = NPC - cc*256;
    const int p = base + ((tid < limit) ? tid : 0);

    {
        float f0 = LD<DT>(pos, (size_t)p*3+0), f1 = LD<DT>(pos, (size_t)p*3+1);
        float f2 = LD<DT>(pos, (size_t)p*3+2), f3 = LD<DT>(refl, p);
        float h[H1];
        #pragma unroll
        for (int j = 0; j < H1; j++)
            h[j] = fmaxf(b1s[j] + f0*w1s[j] + f1*w1s[H1+j] + f2*w1s[2*H1+j] + f3*w1s[3*H1+j], 0.f);
        #pragma unroll
        for (int j = 0; j < H1; j += 2) {
            unsigned v = (unsigned)f2bfb(h[j]) | ((unsigned)f2bfb(h[j+1]) << 16);
            *(unsigned*)&hs[tid*SK96 + j] = v;
        }
        #pragma unroll
        for (int j = H1; j < 96; j += 2) *(unsigned*)&hs[tid*SK96 + j] = 0;
    }
    __syncthreads();

    const int wv = tid >> 6, lane = tid & 63, quad = lane >> 4, l15 = lane & 15;
    f4v acc[4][5];
    #pragma unroll
    for (int mt = 0; mt < 4; mt++)
        #pragma unroll
        for (int nt = 0; nt < 5; nt++) acc[mt][nt] = (f4v){0.f,0.f,0.f,0.f};
    s8v af[4][3];
    #pragma unroll
    for (int mt = 0; mt < 4; mt++)
        #pragma unroll
        for (int ks = 0; ks < 3; ks++)
            af[mt][ks] = *(const s8v*)&hs[(wv*64 + mt*16 + l15)*SK96 + ks*32 + quad*8];
    #pragma unroll
    for (int nt = 0; nt < 5; nt++) {
        #pragma unroll
        for (int ks = 0; ks < 3; ks++) {
            s8v bf_ = *(const s8v*)&gw2gT[(size_t)(nt*16 + l15)*SK96 + ks*32 + quad*8];
            #pragma unroll
            for (int mt = 0; mt < 4; mt++) acc[mt][nt] = MFMA16(af[mt][ks], bf_, acc[mt][nt]);
        }
    }
    #pragma unroll
    for (int nt = 0; nt < 5; nt++) {
        int col = nt*16 + l15;
        float v = acc[0][nt][0];
        #pragma unroll
        for (int mt = 0; mt < 4; mt++)
            #pragma unroll
            for (int r = 0; r < 4; r++) v = fmaxf(v, acc[mt][nt][r]);
        v = fmaxf(v, __shfl_xor(v, 16));
        v = fmaxf(v, __shfl_xor(v, 32));
        if (quad == 0 && col < H1) {
            float o = fmaxf(v + b2s[col], 0.f);
            atomicMax(&pooled[bb*H1 + col], __float_as_int(o));
        }
    }
}

// ---------------- gate logits + gumbel softmax -> y1 ----------------
template<int DT> __global__ void gate2_kernel(
    const int* __restrict__ flag, const int* __restrict__ pooled,
    const void* __restrict__ wg, const void* __restrict__ bg,
    const void* __restrict__ gum, float* __restrict__ y1)
{
    if (*flag != DT) return;
    __shared__ float lg[B_GR][2];
    const int t = threadIdx.x;
    if (t < B_GR*2) {
        int b = t >> 1, g = t & 1;
        float a = LD<DT>(bg, g) + LD<DT>(gum, b*2+g);
        for (int c = 0; c < H1; c++) a += __int_as_float(pooled[b*H1+c]) * LD<DT>(wg, c*2+g);
        lg[b][g] = a;
    }
    __syncthreads();
    if (t < B_GR) {
        float l0 = lg[t][0], l1 = lg[t][1];
        float m = fmaxf(l0, l1);
        float e0 = __expf(l0-m), e1 = __expf(l1-m);
        y1[t] = e1 / (e0 + e1);
    }
}

// ---------------- edge: MFMA chain, single LDS activation buffer ----------------
// block = 8 targets = 128 rows; 256 threads = 4 waves; LDS ~37.8 KB -> 4 blocks/CU
template<int DT> __global__ __launch_bounds__(256) void edge_mfma(
    const int* __restrict__ flag,
    const void* __restrict__ x, const void* __restrict__ pos,
    const void* __restrict__ refl, const float* __restrict__ y1,
    const int* __restrict__ batch,
    const int* __restrict__ idxarr, const int* __restrict__ esrc,
    const void* __restrict__ b1, const void* __restrict__ b2,
    const void* __restrict__ ab1, const void* __restrict__ aw2,
    const unsigned short* __restrict__ gw1T, const unsigned short* __restrict__ gw2T,
    const unsigned short* __restrict__ gaw1T,
    void* __restrict__ out, int M)
{
    if (*flag != DT) return;
    // single activation buffer: A1 -> H -> Ms, all [128][SK128]
    __shared__ __align__(16) unsigned short u2[128*SK128];   // 34.8 KB
    __shared__ float p4[8][4];
    __shared__ int   srow[128];
    __shared__ float b1s[H2], b2s[H2], ab1s[ATTN], aw2s[ATTN];
    __shared__ float scores[128], alpha[128];

    const int tid = threadIdx.x;
    const int m0 = blockIdx.x * 8;

    if (tid < 128) {
        int mm = m0 + (tid >> 4); if (mm >= M) mm = M - 1;
        srow[tid] = esrc[mm*KNN + (tid & 15)];
    }
    if (tid < 32) {
        int tt = tid >> 2, c = tid & 3;
        int mm = m0 + tt; if (mm >= M) mm = M - 1;
        int t_idx = idxarr[mm];
        p4[tt][c] = (c < 3) ? LD<DT>(pos, (size_t)t_idx*3 + c)
                            : y1[batch[t_idx]] * LD<DT>(refl, t_idx);
    }
    if (tid < H2) { b1s[tid] = LD<DT>(b1, tid); b2s[tid] = LD<DT>(b2, tid); }
    if (tid < ATTN) { ab1s[tid] = LD<DT>(ab1, tid); aw2s[tid] = LD<DT>(aw2, tid); }
    __syncthreads();

    // A1 = msg_in [128][96] bf16 into u2 (row stride SK128; cols 96+ never read)
    if (DT) {
        int r = tid >> 1, hf = tid & 1;
        int s = srow[r], tt = r >> 4;
        const uint4* xs = (const uint4*)x;
        uint4* du = (uint4*)u2;           // 17 uint4 per row (136 shorts)
        #pragma unroll
        for (int q = 0; q < 4; q++)
            du[r*17 + hf*4 + q] = xs[(size_t)s*8 + hf*4 + q];
        if (hf == 0) {
            #pragma unroll
            for (int k = 64; k < 68; k++) {
                float v = (k < 67) ? LD<1>(pos, (size_t)s*3 + (k-64)) - p4[tt][k-64]
                                   : y1[batch[s]] * LD<1>(refl, s) - p4[tt][3];
                u2[r*SK128 + k] = f2bfb(v);
            }
        } else {
            #pragma unroll
            for (int k = 68; k < 96; k += 2) *(unsigned*)&u2[r*SK128 + k] = 0;
        }
    } else {
        int r = tid >> 1, half = tid & 1;
        int s = srow[r], tt = r >> 4;
        size_t xb = (size_t)s * IN_CH;
        int k0 = half * 48;
        for (int kk = 0; kk < 48; kk++) {
            int k = k0 + kk;
            float v;
            if (k < IN_CH)       v = LD<DT>(x, xb + k);
            else if (k < 67)     v = LD<DT>(pos, (size_t)s*3 + (k - 64)) - p4[tt][k - 64];
            else if (k == 67)    v = y1[batch[s]] * LD<DT>(refl, s) - p4[tt][3];
            else                 v = 0.f;
            u2[r*SK128 + k] = f2bfb(v);
        }
    }
    __syncthreads();

    const int wv = tid >> 6, lane = tid & 63, quad = lane >> 4, l15 = lane & 15;
    const int rbase = wv * 32;

    // ---- GEMM1: H = relu(A1 @ w1 + b1); A loaded to regs, then overwrite u2 ----
    {
        s8v af[2][3];
        #pragma unroll
        for (int mt = 0; mt < 2; mt++)
            #pragma unroll
            for (int ks = 0; ks < 3; ks++)
                af[mt][ks] = *(const s8v*)&u2[(rbase + mt*16 + l15)*SK128 + ks*32 + quad*8];
        __syncthreads();   // all A-frags in registers before any H write
        f4v acc[2][8];
        #pragma unroll
        for (int mt = 0; mt < 2; mt++)
            #pragma unroll
            for (int nt = 0; nt < 8; nt++) acc[mt][nt] = (f4v){0.f,0.f,0.f,0.f};
        #pragma unroll
        for (int nt = 0; nt < 8; nt++) {
            #pragma unroll
            for (int ks = 0; ks < 3; ks++) {
                s8v bf_ = *(const s8v*)&gw1T[(size_t)(nt*16 + l15)*SK96 + ks*32 + quad*8];
                acc[0][nt] = MFMA16(af[0][ks], bf_, acc[0][nt]);
                acc[1][nt] = MFMA16(af[1][ks], bf_, acc[1][nt]);
            }
        }
        #pragma unroll
        for (int mt = 0; mt < 2; mt++)
            #pragma unroll
            for (int nt = 0; nt < 8; nt++)
                #pragma unroll
                for (int r = 0; r < 4; r++) {
                    int row = rbase + mt*16 + quad*4 + r;
                    int col = nt*16 + l15;
                    u2[row*SK128 + col] = f2bfb(fmaxf(acc[mt][nt][r] + b1s[col], 0.f));
                }
    }
    __syncthreads();

    // ---- GEMM2: Ms = relu(H @ w2 + b2); same single-buffer trick ----
    {
        s8v af[2][4];
        #pragma unroll
        for (int mt = 0; mt < 2; mt++)
            #pragma unroll
            for (int ks = 0; ks < 4; ks++)
                af[mt][ks] = *(const s8v*)&u2[(rbase + mt*16 + l15)*SK128 + ks*32 + quad*8];
        __syncthreads();
        f4v acc[2][8];
        #pragma unroll
        for (int mt = 0; mt < 2; mt++)
            #pragma unroll
            for (int nt = 0; nt < 8; nt++) acc[mt][nt] = (f4v){0.f,0.f,0.f,0.f};
        #pragma unroll
        for (int nt = 0; nt < 8; nt++) {
            #pragma unroll
            for (int ks = 0; ks < 4; ks++) {
                s8v bf_ = *(const s8v*)&gw2T[(size_t)(nt*16 + l15)*SK128 + ks*32 + quad*8];
                acc[0][nt] = MFMA16(af[0][ks], bf_, acc[0][nt]);
                acc[1][nt] = MFMA16(af[1][ks], bf_, acc[1][nt]);
            }
        }
        #pragma unroll
        for (int mt = 0; mt < 2; mt++)
            #pragma unroll
            for (int nt = 0; nt < 8; nt++)
                #pragma unroll
                for (int r = 0; r < 4; r++) {
                    int row = rbase + mt*16 + quad*4 + r;
                    int col = nt*16 + l15;
                    u2[row*SK128 + col] = f2bfb(fmaxf(acc[mt][nt][r] + b2s[col], 0.f));
                }
    }
    __syncthreads();

    // ---- GEMM3: scores via in-register shuffle reduction (no LDS att array) ----
    {
        s8v af[2][4];
        #pragma unroll
        for (int mt = 0; mt < 2; mt++)
            #pragma unroll
            for (int ks = 0; ks < 4; ks++)
                af[mt][ks] = *(const s8v*)&u2[(rbase + mt*16 + l15)*SK128 + ks*32 + quad*8];
        f4v acc[2][2];
        #pragma unroll
        for (int mt = 0; mt < 2; mt++)
            #pragma unroll
            for (int nt = 0; nt < 2; nt++) acc[mt][nt] = (f4v){0.f,0.f,0.f,0.f};
        #pragma unroll
        for (int nt = 0; nt < 2; nt++) {
            #pragma unroll
            for (int ks = 0; ks < 4; ks++) {
                s8v bf_ = *(const s8v*)&gaw1T[(size_t)(nt*16 + l15)*SK128 + ks*32 + quad*8];
                acc[0][nt] = MFMA16(af[0][ks], bf_, acc[0][nt]);
                acc[1][nt] = MFMA16(af[1][ks], bf_, acc[1][nt]);
            }
        }
        #pragma unroll
        for (int mt = 0; mt < 2; mt++)
            #pragma unroll
            for (int r = 0; r < 4; r++) {
                float s = 0.f;
                #pragma unroll
                for (int nt = 0; nt < 2; nt++) {
                    int col = nt*16 + l15;
                    s += tanhf(acc[mt][nt][r] + ab1s[col]) * aw2s[col];
                }
                s += __shfl_xor(s, 1);
                s += __shfl_xor(s, 2);
                s += __shfl_xor(s, 4);
                s += __shfl_xor(s, 8);
                if (l15 == 0) scores[rbase + mt*16 + quad*4 + r] = s;
            }
    }
    __syncthreads();

    if (tid < 128) {
        int base = (tid >> 4) << 4;
        float mx = scores[base];
        #pragma unroll
        for (int j = 1; j < KNN; j++) mx = fmaxf(mx, scores[base+j]);
        float den = 0.f;
        #pragma unroll
        for (int j = 0; j < KNN; j++) den += __expf(scores[base+j] - mx);
        alpha[tid] = __expf(scores[tid] - mx) / den;
    }
    __syncthreads();

    // ---- aggregate: vectorized b128 LDS reads; packed bf16 global stores ----
    if (tid < 128) {
        int tt = tid >> 4, c0 = (tid & 15) * 8;
        int mm = m0 + tt;
        float a[8] = {0,0,0,0,0,0,0,0};
        #pragma unroll
        for (int j = 0; j < KNN; j++) {
            float al = alpha[tt*16 + j];
            s8v v = *(const s8v*)&u2[(tt*16 + j)*SK128 + c0];
            #pragma unroll
            for (int e = 0; e < 8; e++) a[e] += al * bfb2f((unsigned short)v[e]);
        }
        if (mm < M) {
            if (DT) {
                unsigned short pk[8];
                #pragma unroll
                for (int e = 0; e < 8; e++) pk[e] = f2bfb(a[e]);
                *(uint4*)((bf16*)out + (size_t)mm*H2 + c0) = *(const uint4*)pk;
            } else {
                #pragma unroll
                for (int e = 0; e < 8; e++) ST<0>(out, (size_t)mm*H2 + c0 + e, a[e]);
            }
        }
    } else if (tid < 160) {
        int t = tid - 128;
        int tt = t >> 2, c = t & 3;
        int mm = m0 + tt;
        if (mm < M) {
            if (c < 3) ST<DT>(out, (size_t)M*128 + mm*3 + c, p4[tt][c]);
            else {
                ST<DT>(out, (size_t)M*131 + mm, (float)batch[idxarr[mm]]);
                ST<DT>(out, (size_t)M*132 + mm, p4[tt][3]);
            }
        }
    }
}

// ---------------- post: MFMA, 32 targets/block ----------------
template<int DT> __global__ __launch_bounds__(256) void post_mfma(
    const int* __restrict__ flag,
    const unsigned short* __restrict__ expwT, const unsigned short* __restrict__ d1pwT,
    const unsigned short* __restrict__ d2pwT, const unsigned short* __restrict__ pjwT,
    const float4* __restrict__ C1, const float2* __restrict__ C2,
    const float2* __restrict__ C3, const float2* __restrict__ C4,
    void* __restrict__ out, int M)
{
    if (*flag != DT) return;
    __shared__ __align__(16) unsigned short zs[32*SK512];
    __shared__ __align__(16) unsigned short a0[32*SK128];
    const int tid = threadIdx.x;
    const int m0 = blockIdx.x * 32;

    {
        int r = tid >> 3;
        int c0 = (tid & 7) * 16;
        int mm = m0 + r;
        for (int c = c0; c < c0+16; c++) {
            float v = (mm < M) ? LD<DT>(out, (size_t)mm*RNN + c) : 0.f;
            a0[r*SK128 + c] = f2bfb(v);
        }
        if ((tid & 7) == 7) for (int c = RNN; c < SK128; c++) a0[r*SK128 + c] = 0;
    }
    __syncthreads();

    const int wv = tid >> 6, lane = tid & 63, quad = lane >> 4, l15 = lane & 15;
    const int nbase = wv * 128;

    f4v acc[2][8];

    // exp GEMM
    #pragma unroll
    for (int mt = 0; mt < 2; mt++)
        #pragma unroll
        for (int nt = 0; nt < 8; nt++) acc[mt][nt] = (f4v){0.f,0.f,0.f,0.f};
    #pragma unroll
    for (int ks = 0; ks < 4; ks++) {
        s8v af0 = *(const s8v*)&a0[(l15)*SK128 + ks*32 + quad*8];
        s8v af1 = *(const s8v*)&a0[(16+l15)*SK128 + ks*32 + quad*8];
        #pragma unroll
        for (int nt = 0; nt < 8; nt++) {
            s8v bf_ = *(const s8v*)&expwT[(size_t)(nbase + nt*16 + l15)*SK128 + ks*32 + quad*8];
            acc[0][nt] = MFMA16(af0, bf_, acc[0][nt]);
            acc[1][nt] = MFMA16(af1, bf_, acc[1][nt]);
        }
    }
    #pragma unroll
    for (int nt = 0; nt < 8; nt++) {
        int col = nbase + nt*16 + l15;
        float4 cf = C1[col];
        #pragma unroll
        for (int mt = 0; mt < 2; mt++)
            #pragma unroll
            for (int r = 0; r < 4; r++) {
                int row = mt*16 + quad*4 + r;
                float u = fmaxf(cf.x*acc[mt][nt][r] + cf.y, 0.f);
                float d = fmaxf(cf.z*u + cf.w, 0.f);
                zs[row*SK512 + col] = f2bfb(d);
            }
    }
    __syncthreads();

    // ds1 pw GEMM
    #pragma unroll
    for (int mt = 0; mt < 2; mt++)
        #pragma unroll
        for (int nt = 0; nt < 8; nt++) acc[mt][nt] = (f4v){0.f,0.f,0.f,0.f};
    for (int ks = 0; ks < 16; ks++) {
        s8v af0 = *(const s8v*)&zs[(l15)*SK512 + ks*32 + quad*8];
        s8v af1 = *(const s8v*)&zs[(16+l15)*SK512 + ks*32 + quad*8];
        #pragma unroll
        for (int nt = 0; nt < 8; nt++) {
            s8v bf_ = *(const s8v*)&d1pwT[(size_t)(nbase + nt*16 + l15)*SK512 + ks*32 + quad*8];
            acc[0][nt] = MFMA16(af0, bf_, acc[0][nt]);
            acc[1][nt] = MFMA16(af1, bf_, acc[1][nt]);
        }
    }
    __syncthreads();
    #pragma unroll
    for (int nt = 0; nt < 8; nt++) {
        int col = nbase + nt*16 + l15;
        float2 cf = C2[col];
        #pragma unroll
        for (int mt = 0; mt < 2; mt++)
            #pragma unroll
            for (int r = 0; r < 4; r++) {
                int row = mt*16 + quad*4 + r;
                zs[row*SK512 + col] = f2bfb(fmaxf(cf.x*acc[mt][nt][r] + cf.y, 0.f));
            }
    }
    __syncthreads();

    // ds2 pw GEMM
    #pragma unroll
    for (int mt = 0; mt < 2; mt++)
        #pragma unroll
        for (int nt = 0; nt < 8; nt++) acc[mt][nt] = (f4v){0.f,0.f,0.f,0.f};
    for (int ks = 0; ks < 16; ks++) {
        s8v af0 = *(const s8v*)&zs[(l15)*SK512 + ks*32 + quad*8];
        s8v af1 = *(const s8v*)&zs[(16+l15)*SK512 + ks*32 + quad*8];
        #pragma unroll
        for (int nt = 0; nt < 8; nt++) {
            s8v bf_ = *(const s8v*)&d2pwT[(size_t)(nbase + nt*16 + l15)*SK512 + ks*32 + quad*8];
            acc[0][nt] = MFMA16(af0, bf_, acc[0][nt]);
            acc[1][nt] = MFMA16(af1, bf_, acc[1][nt]);
        }
    }
    __syncthreads();
    #pragma unroll
    for (int nt = 0; nt < 8; nt++) {
        int col = nbase + nt*16 + l15;
        float2 cf = C3[col];
        #pragma unroll
        for (int mt = 0; mt < 2; mt++)
            #pragma unroll
            for (int r = 0; r < 4; r++) {
                int row = mt*16 + quad*4 + r;
                zs[row*SK512 + col] = f2bfb(cf.x*acc[mt][nt][r] + cf.y);
            }
    }
    __syncthreads();

    // proj GEMM + residual
    {
        f4v pacc[2][2];
        #pragma unroll
        for (int mt = 0; mt < 2; mt++)
            #pragma unroll
            for (int nt = 0; nt < 2; nt++) pacc[mt][nt] = (f4v){0.f,0.f,0.f,0.f};
        for (int ks = 0; ks < 16; ks++) {
            s8v af0 = *(const s8v*)&zs[(l15)*SK512 + ks*32 + quad*8];
            s8v af1 = *(const s8v*)&zs[(16+l15)*SK512 + ks*32 + quad*8];
            #pragma unroll
            for (int nt = 0; nt < 2; nt++) {
                s8v bf_ = *(const s8v*)&pjwT[(size_t)(wv*32 + nt*16 + l15)*SK512 + ks*32 + quad*8];
                pacc[0][nt] = MFMA16(af0, bf_, pacc[0][nt]);
                pacc[1][nt] = MFMA16(af1, bf_, pacc[1][nt]);
            }
        }
        #pragma unroll
        for (int nt = 0; nt < 2; nt++) {
            int col = wv*32 + nt*16 + l15;
            float2 cf = C4[col];
            #pragma unroll
            for (int mt = 0; mt < 2; mt++)
                #pragma unroll
                for (int r = 0; r < 4; r++) {
                    int row = mt*16 + quad*4 + r;
                    int mm = m0 + row;
                    if (mm < M) {
                        float agv = bfb2f(a0[row*SK128 + col]);
                        float o = fmaxf(cf.x*pacc[mt][nt][r] + cf.y + agv, 0.f);
                        ST<DT>(out, (size_t)mm*RNN + col, o);
                    }
                }
        }
    }
}

extern "C" void kernel_launch(void* const* d_in, const int* in_sizes, int n_in,
                              void* d_out, int out_size, void* d_ws, size_t ws_size,
                              hipStream_t stream)
{
    const void* x    = d_in[0];
    const void* pos  = d_in[1];
    const void* refl = d_in[2];
    const void* gum  = d_in[3];
    const void* gw1  = d_in[4];
    const void* gb1  = d_in[5];
    const void* gw2  = d_in[6];
    const void* gb2  = d_in[7];
    const void* gwg  = d_in[8];
    const void* gbg  = d_in[9];
    const void* lw1  = d_in[10];
    const void* lb1  = d_in[11];
    const void* lw2  = d_in[12];
    const void* lb2  = d_in[13];
    const void* aw1  = d_in[14];
    const void* ab1  = d_in[15];
    const void* aw2  = d_in[16];
    const void* expw = d_in[17];
    const void* expb = d_in[18];
    const void* expbn= d_in[19];
    const void* d1dw = d_in[20];
    const void* d1bn1= d_in[21];
    const void* d1pw = d_in[22];
    const void* d1pb = d_in[23];
    const void* d1bn2= d_in[24];
    const void* bbn1 = d_in[25];
    const void* d2dw = d_in[26];
    const void* d2bn1= d_in[27];
    const void* d2pw = d_in[28];
    const void* d2pb = d_in[29];
    const void* d2bn2= d_in[30];
    const void* bbn2 = d_in[31];
    const void* pjw  = d_in[32];
    const void* pjb  = d_in[33];
    const void* pjbn = d_in[34];
    const int* batch = (const int*)d_in[35];
    const int* idxp  = (const int*)d_in[36];
    const int* eidx  = (const int*)d_in[37];

    const int N = in_sizes[2];
    const int M = in_sizes[36];
    const int NPC = N / B_GR;
    const int CPB = (NPC + 255) / 256;

    // ws layout (bytes)
    char* wsb = (char*)d_ws;
    int*  flag   = (int*)wsb;
    int*  pooled = (int*)(wsb + 16);
    float* y1    = (float*)(wsb + 2304);
    unsigned short* w1T   = (unsigned short*)(wsb + 2368);
    unsigned short* w2T   = w1T + W1T_E;
    unsigned short* aw1T  = w2T + W2T_E;
    unsigned short* expwT = aw1T + AW1T_E;
    unsigned short* d1pwT = expwT + EXPT_E;
    unsigned short* d2pwT = d1pwT + D1T_E;
    unsigned short* pjwT  = d2pwT + D2T_E;
    unsigned short* gw2gT = pjwT + PJT_E;
    float4* C1 = (float4*)(gw2gT + GW2T_E + 8);
    float2* C2 = (float2*)(C1 + E4);
    float2* C3 = C2 + E4;
    float2* C4 = C3 + E4;

    prep_kernel<<<1, 256, 0, stream>>>(pos, flag, pooled);

    trans_kernel<0><<<512, 256, 0, stream>>>(flag, lw1, lw2, aw1, expw, d1pw, d2pw, pjw, gw2,
                                             w1T, w2T, aw1T, expwT, d1pwT, d2pwT, pjwT, gw2gT);
    trans_kernel<1><<<512, 256, 0, stream>>>(flag, lw1, lw2, aw1, expw, d1pw, d2pw, pjw, gw2,
                                             w1T, w2T, aw1T, expwT, d1pwT, d2pwT, pjwT, gw2gT);

    coef_kernel<0><<<2, 256, 0, stream>>>(flag, expb, expbn, d1dw, d1bn1, d1pb, d1bn2, bbn1,
                                          d2dw, d2bn1, d2pb, d2bn2, bbn2, pjb, pjbn,
                                          C1, C2, C3, C4);
    coef_kernel<1><<<2, 256, 0, stream>>>(flag, expb, expbn, d1dw, d1bn1, d1pb, d1bn2, bbn1,
                                          d2dw, d2bn1, d2pb, d2bn2, bbn2, pjb, pjbn,
                                          C1, C2, C3, C4);

    gate_mfma<0><<<B_GR*CPB, 256, 0, stream>>>(flag, pos, refl, gw1, gb1, gb2, gw2gT, pooled, NPC, CPB);
    gate_mfma<1><<<B_GR*CPB, 256, 0, stream>>>(flag, pos, refl, gw1, gb1, gb2, gw2gT, pooled, NPC, CPB);

    gate2_kernel<0><<<1, 64, 0, stream>>>(flag, pooled, gwg, gbg, gum, y1);
    gate2_kernel<1><<<1, 64, 0, stream>>>(flag, pooled, gwg, gbg, gum, y1);

    const int EB = (M + 7) / 8;
    edge_mfma<0><<<EB, 256, 0, stream>>>(flag, x, pos, refl, y1, batch, idxp, eidx,
                                         lb1, lb2, ab1, aw2, w1T, w2T, aw1T, d_out, M);
    edge_mfma<1><<<EB, 256, 0, stream>>>(flag, x, pos, refl, y1, batch, idxp, eidx,
                                         lb1, lb2, ab1, aw2, w1T, w2T, aw1T, d_out, M);

    const int PB = (M + 31) / 32;
    post_mfma<0><<<PB, 256, 0, stream>>>(flag, expwT, d1pwT, d2pwT, pjwT, C1, C2, C3, C4, d_out, M);
    post_mfma<1><<<PB, 256, 0, stream>>>(flag, expwT, d1pwT, d2pwT, pjwT, C1, C2, C3, C4, d_out, M);
}

// Round 7
// 472.945 us; speedup vs baseline: 1.1858x; 1.1858x over previous
//
#include <hip/hip_runtime.h>
#include <hip/hip_bf16.h>

typedef __hip_bfloat16 bf16;

#define B_GR 8
#define IN_CH 64
#define H1 68
#define H2 128
#define ATTN 32
#define E4 512
#define RNN 128
#define KNN 16
#define EPSV 1e-5f

typedef __attribute__((ext_vector_type(8))) short s8v;
typedef __attribute__((ext_vector_type(4))) float f4v;
#define MFMA16(a,b,c) __builtin_amdgcn_mfma_f32_16x16x32_bf16(a,b,c,0,0,0)

// strides (elements) — +8 pad keeps 16B alignment, breaks pow2 banks
#define SK96 104
#define SK128 136
#define SK512 520

template<int DT> __device__ __forceinline__ float LD(const void* p, size_t i) {
    if (DT) return __bfloat162float(((const bf16*)p)[i]);
    return ((const float*)p)[i];
}
template<int DT> __device__ __forceinline__ void ST(void* p, size_t i, float v) {
    if (DT) ((bf16*)p)[i] = __float2bfloat16(v);
    else    ((float*)p)[i] = v;
}
__device__ __forceinline__ unsigned short f2bfb(float f) {
    unsigned u = __float_as_uint(f);
    unsigned r = (u + 0x7FFFu + ((u >> 16) & 1u)) >> 16;
    return (unsigned short)r;
}
__device__ __forceinline__ float bfb2f(unsigned short u) {
    return __uint_as_float(((unsigned)u) << 16);
}
__device__ __forceinline__ float fast_tanh(float x) {
    x = fminf(fmaxf(x, -12.f), 12.f);
    float e = __expf(2.f * x);
    return (e - 1.f) / (e + 1.f);
}

// ---------------- prep: dtype detect + zero pooled ----------------
__global__ void prep_kernel(const void* pos, int* flag, int* pooled) {
    const int tid = threadIdx.x;
    for (int i = tid; i < B_GR*H1; i += 256) pooled[i] = 0;
    if (tid == 0) {
        const unsigned* w = (const unsigned*)pos;
        int ok = 1;
        #pragma unroll 8
        for (int i = 0; i < 256; i++) {
            float f = __uint_as_float((w[i] & 0xFFFFu) << 16);
            if (!(f >= -0.01f && f <= 10.05f)) ok = 0;
        }
        *flag = ok;
    }
}

// ---------------- transpose+convert weights into ws (bf16 bits) ----------------
#define W1T_E (128*SK96)
#define W2T_E (128*SK128)
#define AW1T_E (32*SK128)
#define EXPT_E (512*SK128)
#define D1T_E (512*SK512)
#define D2T_E (512*SK512)
#define PJT_E (128*SK512)
#define GW2T_E (80*SK96)
template<int DT> __global__ __launch_bounds__(256) void trans_kernel(
    const int* __restrict__ flag,
    const void* __restrict__ w1, const void* __restrict__ w2, const void* __restrict__ aw1,
    const void* __restrict__ expw, const void* __restrict__ d1pw,
    const void* __restrict__ d2pw, const void* __restrict__ pjw,
    const void* __restrict__ gw2,
    unsigned short* __restrict__ w1T, unsigned short* __restrict__ w2T,
    unsigned short* __restrict__ aw1T, unsigned short* __restrict__ expwT,
    unsigned short* __restrict__ d1pwT, unsigned short* __restrict__ d2pwT,
    unsigned short* __restrict__ pjwT, unsigned short* __restrict__ gw2gT)
{
    if (*flag != DT) return;
    const int T0 = W1T_E, T1 = T0+W2T_E, T2 = T1+AW1T_E, T3 = T2+EXPT_E,
              T4 = T3+D1T_E, T5 = T4+D2T_E, T6 = T5+PJT_E, T7 = T6+GW2T_E;
    for (int i = blockIdx.x*256 + threadIdx.x; i < T7; i += gridDim.x*256) {
        if (i < T0) {
            int n = i / SK96, k = i - n*SK96;
            w1T[i] = (k < H1) ? f2bfb(LD<DT>(w1, (size_t)k*H2 + n)) : 0;
        } else if (i < T1) {
            int j = i - T0; int n = j / SK128, k = j - n*SK128;
            w2T[j] = (k < H2) ? f2bfb(LD<DT>(w2, (size_t)k*H2 + n)) : 0;
        } else if (i < T2) {
            int j = i - T1; int n = j / SK128, k = j - n*SK128;
            aw1T[j] = (k < H2) ? f2bfb(LD<DT>(aw1, (size_t)k*ATTN + n)) : 0;
        } else if (i < T3) {
            int j = i - T2; int n = j / SK128, k = j - n*SK128;
            expwT[j] = (k < RNN) ? f2bfb(LD<DT>(expw, (size_t)k*E4 + n)) : 0;
        } else if (i < T4) {
            int j = i - T3; int n = j / SK512, k = j - n*SK512;
            d1pwT[j] = (k < E4) ? f2bfb(LD<DT>(d1pw, (size_t)k*E4 + n)) : 0;
        } else if (i < T5) {
            int j = i - T4; int n = j / SK512, k = j - n*SK512;
            d2pwT[j] = (k < E4) ? f2bfb(LD<DT>(d2pw, (size_t)k*E4 + n)) : 0;
        } else if (i < T6) {
            int j = i - T5; int n = j / SK512, k = j - n*SK512;
            pjwT[j] = (k < E4) ? f2bfb(LD<DT>(pjw, (size_t)k*RNN + n)) : 0;
        } else {
            int j = i - T6; int n = j / SK96, k = j - n*SK96;
            gw2gT[j] = (k < H1 && n < H1) ? f2bfb(LD<DT>(gw2, (size_t)k*H1 + n)) : 0;
        }
    }
}

// ---------------- folded per-column affine coefficients for post ----------------
template<int DT> __global__ void coef_kernel(
    const int* __restrict__ flag,
    const void* __restrict__ expb, const void* __restrict__ expbn,
    const void* __restrict__ d1dw, const void* __restrict__ d1bn1,
    const void* __restrict__ d1pb, const void* __restrict__ d1bn2, const void* __restrict__ bbn1,
    const void* __restrict__ d2dw, const void* __restrict__ d2bn1,
    const void* __restrict__ d2pb, const void* __restrict__ d2bn2, const void* __restrict__ bbn2,
    const void* __restrict__ pjb, const void* __restrict__ pjbn,
    float4* __restrict__ C1, float2* __restrict__ C2, float2* __restrict__ C3,
    float2* __restrict__ C4)
{
    if (*flag != DT) return;
    int c = blockIdx.x*256 + threadIdx.x;
    if (c < E4) {
        float a_e = LD<DT>(expbn,c) * rsqrtf(LD<DT>(expbn,3*E4+c)+EPSV);
        float t0  = a_e*(LD<DT>(expb,c) - LD<DT>(expbn,2*E4+c)) + LD<DT>(expbn,E4+c);
        float a1 = LD<DT>(d1bn1,c) * rsqrtf(LD<DT>(d1bn1,3*E4+c)+EPSV);
        float s1 = a1 * LD<DT>(d1dw,c);
        float t1 = a1*(LD<DT>(d1dw,E4+c) - LD<DT>(d1bn1,2*E4+c)) + LD<DT>(d1bn1,E4+c);
        C1[c] = make_float4(a_e, t0, s1, t1);
        float a2 = LD<DT>(d1bn2,c) * rsqrtf(LD<DT>(d1bn2,3*E4+c)+EPSV);
        float t2 = a2*(LD<DT>(d1pb,c) - LD<DT>(d1bn2,2*E4+c)) + LD<DT>(d1bn2,E4+c);
        float a3 = LD<DT>(bbn1,c) * rsqrtf(LD<DT>(bbn1,3*E4+c)+EPSV);
        float S2 = a3*a2;
        float T2 = a3*(t2 - LD<DT>(bbn1,2*E4+c)) + LD<DT>(bbn1,E4+c);
        float a4 = LD<DT>(d2bn1,c) * rsqrtf(LD<DT>(d2bn1,3*E4+c)+EPSV);
        float sdw = a4 * LD<DT>(d2dw,c);
        float tdw = a4*(LD<DT>(d2dw,E4+c) - LD<DT>(d2bn1,2*E4+c)) + LD<DT>(d2bn1,E4+c);
        C2[c] = make_float2(sdw*S2, sdw*T2 + tdw);
        float a5 = LD<DT>(d2bn2,c) * rsqrtf(LD<DT>(d2bn2,3*E4+c)+EPSV);
        float t5 = a5*(LD<DT>(d2pb,c) - LD<DT>(d2bn2,2*E4+c)) + LD<DT>(d2bn2,E4+c);
        float a6 = LD<DT>(bbn2,c) * rsqrtf(LD<DT>(bbn2,3*E4+c)+EPSV);
        C3[c] = make_float2(a6*a5, a6*(t5 - LD<DT>(bbn2,2*E4+c)) + LD<DT>(bbn2,E4+c));
    }
    if (c < RNN) {
        float ap = LD<DT>(pjbn,c) * rsqrtf(LD<DT>(pjbn,3*RNN+c)+EPSV);
        C4[c] = make_float2(ap, ap*(LD<DT>(pjb,c) - LD<DT>(pjbn,2*RNN+c)) + LD<DT>(pjbn,RNN+c));
    }
}

// ---------------- gate: layer1 VALU + layer2 MFMA + segment max ----------------
template<int DT> __global__ __launch_bounds__(256) void gate_mfma(
    const int* __restrict__ flag,
    const void* __restrict__ pos, const void* __restrict__ refl,
    const void* __restrict__ w1, const void* __restrict__ b1, const void* __restrict__ b2g,
    const unsigned short* __restrict__ gw2gT,
    int* __restrict__ pooled, int NPC, int CPB)
{
    if (*flag != DT) return;
    __shared__ __align__(16) unsigned short hs[256*SK96];
    __shared__ float w1s[4*H1], b1s[H1], b2s[H1];
    const int tid = threadIdx.x;
    for (int i = tid; i < 4*H1; i += 256) w1s[i] = LD<DT>(w1, i);
    if (tid < H1) { b1s[tid] = LD<DT>(b1, tid); b2s[tid] = LD<DT>(b2g, tid); }
    __syncthreads();

    const int bb = blockIdx.x / CPB;
    const int cc = blockIdx.x % CPB;
    const int base = bb*NPC + cc*256;
    const int limit = NPC - cc*256;
    const int p = base + ((tid < limit) ? tid : 0);

    {
        float f0 = LD<DT>(pos, (size_t)p*3+0), f1 = LD<DT>(pos, (size_t)p*3+1);
        float f2 = LD<DT>(pos, (size_t)p*3+2), f3 = LD<DT>(refl, p);
        float h[H1];
        #pragma unroll
        for (int j = 0; j < H1; j++)
            h[j] = fmaxf(b1s[j] + f0*w1s[j] + f1*w1s[H1+j] + f2*w1s[2*H1+j] + f3*w1s[3*H1+j], 0.f);
        #pragma unroll
        for (int j = 0; j < H1; j += 2) {
            unsigned v = (unsigned)f2bfb(h[j]) | ((unsigned)f2bfb(h[j+1]) << 16);
            *(unsigned*)&hs[tid*SK96 + j] = v;
        }
        #pragma unroll
        for (int j = H1; j < 96; j += 2) *(unsigned*)&hs[tid*SK96 + j] = 0;
    }
    __syncthreads();

    const int wv = tid >> 6, lane = tid & 63, quad = lane >> 4, l15 = lane & 15;
    f4v acc[4][5];
    #pragma unroll
    for (int mt = 0; mt < 4; mt++)
        #pragma unroll
        for (int nt = 0; nt < 5; nt++) acc[mt][nt] = (f4v){0.f,0.f,0.f,0.f};
    s8v af[4][3];
    #pragma unroll
    for (int mt = 0; mt < 4; mt++)
        #pragma unroll
        for (int ks = 0; ks < 3; ks++)
            af[mt][ks] = *(const s8v*)&hs[(wv*64 + mt*16 + l15)*SK96 + ks*32 + quad*8];
    #pragma unroll
    for (int nt = 0; nt < 5; nt++) {
        #pragma unroll
        for (int ks = 0; ks < 3; ks++) {
            s8v bf_ = *(const s8v*)&gw2gT[(size_t)(nt*16 + l15)*SK96 + ks*32 + quad*8];
            #pragma unroll
            for (int mt = 0; mt < 4; mt++) acc[mt][nt] = MFMA16(af[mt][ks], bf_, acc[mt][nt]);
        }
    }
    #pragma unroll
    for (int nt = 0; nt < 5; nt++) {
        int col = nt*16 + l15;
        float v = acc[0][nt][0];
        #pragma unroll
        for (int mt = 0; mt < 4; mt++)
            #pragma unroll
            for (int r = 0; r < 4; r++) v = fmaxf(v, acc[mt][nt][r]);
        v = fmaxf(v, __shfl_xor(v, 16));
        v = fmaxf(v, __shfl_xor(v, 32));
        if (quad == 0 && col < H1) {
            float o = fmaxf(v + b2s[col], 0.f);
            atomicMax(&pooled[bb*H1 + col], __float_as_int(o));
        }
    }
}

// ---------------- gate logits + gumbel softmax -> y1 ----------------
template<int DT> __global__ void gate2_kernel(
    const int* __restrict__ flag, const int* __restrict__ pooled,
    const void* __restrict__ wg, const void* __restrict__ bg,
    const void* __restrict__ gum, float* __restrict__ y1)
{
    if (*flag != DT) return;
    __shared__ float lg[B_GR][2];
    const int t = threadIdx.x;
    if (t < B_GR*2) {
        int b = t >> 1, g = t & 1;
        float a = LD<DT>(bg, g) + LD<DT>(gum, b*2+g);
        for (int c = 0; c < H1; c++) a += __int_as_float(pooled[b*H1+c]) * LD<DT>(wg, c*2+g);
        lg[b][g] = a;
    }
    __syncthreads();
    if (t < B_GR) {
        float l0 = lg[t][0], l1 = lg[t][1];
        float m = fmaxf(l0, l1);
        float e0 = __expf(l0-m), e1 = __expf(l1-m);
        y1[t] = e1 / (e0 + e1);
    }
}

// ---------------- edge: barrier-free, wave-private (2 targets per wave) ----------------
// block = 256 threads = 4 waves = 8 targets. NO __syncthreads in the hot path:
// each wave owns rows [wv*32, wv*32+32) of u2; within-wave LDS RAW is ordered by
// compiler-inserted lgkmcnt waits. A-fragments load straight from global x.
template<int DT> __global__ __launch_bounds__(256) void edge_mfma(
    const int* __restrict__ flag,
    const void* __restrict__ x, const void* __restrict__ pos,
    const void* __restrict__ refl, const float* __restrict__ y1,
    const int* __restrict__ batch,
    const int* __restrict__ idxarr, const int* __restrict__ esrc,
    const void* __restrict__ b1, const void* __restrict__ b2,
    const void* __restrict__ ab1, const void* __restrict__ aw2,
    const unsigned short* __restrict__ gw1T, const unsigned short* __restrict__ gw2T,
    const unsigned short* __restrict__ gaw1T,
    void* __restrict__ out, int M)
{
    if (*flag != DT) return;
    __shared__ __align__(16) unsigned short u2[128*SK128];   // 34.8 KB, wave-private strips
    __shared__ float ssc[4][2][16];                           // per-wave score scratch

    const int tid = threadIdx.x;
    const int wv = tid >> 6, lane = tid & 63, quad = lane >> 4, l15 = lane & 15;
    const int m0 = blockIdx.x * 8 + wv * 2;
    const int rb = wv * 32;   // this wave's LDS row base

    // ---- per-target setup + A-fragments straight from global ----
    s8v af[2][3];
    int mcl[2];
    float p4v[2][4];
    #pragma unroll
    for (int t = 0; t < 2; t++) {
        int mm = m0 + t; if (mm >= M) mm = M - 1;
        mcl[t] = mm;
        int t_idx = idxarr[mm];
        p4v[t][0] = LD<DT>(pos, (size_t)t_idx*3 + 0);
        p4v[t][1] = LD<DT>(pos, (size_t)t_idx*3 + 1);
        p4v[t][2] = LD<DT>(pos, (size_t)t_idx*3 + 2);
        p4v[t][3] = y1[batch[t_idx]] * LD<DT>(refl, t_idx);
        int s = esrc[mm*KNN + l15];   // lane l15 <-> neighbor row
        if (DT) {
            const unsigned short* xs = (const unsigned short*)x + (size_t)s*IN_CH;
            af[t][0] = *(const s8v*)(xs + quad*8);
            af[t][1] = *(const s8v*)(xs + 32 + quad*8);
        } else {
            unsigned short tmp0[8], tmp1[8];
            #pragma unroll
            for (int e = 0; e < 8; e++) {
                tmp0[e] = f2bfb(LD<0>(x, (size_t)s*IN_CH + quad*8 + e));
                tmp1[e] = f2bfb(LD<0>(x, (size_t)s*IN_CH + 32 + quad*8 + e));
            }
            af[t][0] = *(const s8v*)tmp0;
            af[t][1] = *(const s8v*)tmp1;
        }
        s8v a2 = (s8v){0,0,0,0,0,0,0,0};
        if (quad == 0) {
            a2[0] = (short)f2bfb(LD<DT>(pos, (size_t)s*3 + 0) - p4v[t][0]);
            a2[1] = (short)f2bfb(LD<DT>(pos, (size_t)s*3 + 1) - p4v[t][1]);
            a2[2] = (short)f2bfb(LD<DT>(pos, (size_t)s*3 + 2) - p4v[t][2]);
            a2[3] = (short)f2bfb(y1[batch[s]] * LD<DT>(refl, s) - p4v[t][3]);
        }
        af[t][2] = a2;
    }

    // ---- GEMM1: H = relu(msg_in @ w1 + b1) -> u2 rows [rb + t*16 ...] ----
    {
        f4v acc[2][8];
        #pragma unroll
        for (int t = 0; t < 2; t++)
            #pragma unroll
            for (int nt = 0; nt < 8; nt++) acc[t][nt] = (f4v){0.f,0.f,0.f,0.f};
        #pragma unroll
        for (int nt = 0; nt < 8; nt++) {
            #pragma unroll
            for (int ks = 0; ks < 3; ks++) {
                s8v bf_ = *(const s8v*)&gw1T[(size_t)(nt*16 + l15)*SK96 + ks*32 + quad*8];
                acc[0][nt] = MFMA16(af[0][ks], bf_, acc[0][nt]);
                acc[1][nt] = MFMA16(af[1][ks], bf_, acc[1][nt]);
            }
        }
        #pragma unroll
        for (int nt = 0; nt < 8; nt++) {
            int col = nt*16 + l15;
            float bb = LD<DT>(b1, col);
            #pragma unroll
            for (int t = 0; t < 2; t++)
                #pragma unroll
                for (int r = 0; r < 4; r++) {
                    int row = rb + t*16 + quad*4 + r;
                    u2[row*SK128 + col] = f2bfb(fmaxf(acc[t][nt][r] + bb, 0.f));
                }
        }
    }

    // ---- GEMM2: Ms = relu(H @ w2 + b2); read H (lgkm-ordered), overwrite rows ----
    {
        s8v af2[2][4];
        #pragma unroll
        for (int t = 0; t < 2; t++)
            #pragma unroll
            for (int ks = 0; ks < 4; ks++)
                af2[t][ks] = *(const s8v*)&u2[(rb + t*16 + l15)*SK128 + ks*32 + quad*8];
        f4v acc[2][8];
        #pragma unroll
        for (int t = 0; t < 2; t++)
            #pragma unroll
            for (int nt = 0; nt < 8; nt++) acc[t][nt] = (f4v){0.f,0.f,0.f,0.f};
        #pragma unroll
        for (int nt = 0; nt < 8; nt++) {
            #pragma unroll
            for (int ks = 0; ks < 4; ks++) {
                s8v bf_ = *(const s8v*)&gw2T[(size_t)(nt*16 + l15)*SK128 + ks*32 + quad*8];
                acc[0][nt] = MFMA16(af2[0][ks], bf_, acc[0][nt]);
                acc[1][nt] = MFMA16(af2[1][ks], bf_, acc[1][nt]);
            }
        }
        #pragma unroll
        for (int nt = 0; nt < 8; nt++) {
            int col = nt*16 + l15;
            float bb = LD<DT>(b2, col);
            #pragma unroll
            for (int t = 0; t < 2; t++)
                #pragma unroll
                for (int r = 0; r < 4; r++) {
                    int row = rb + t*16 + quad*4 + r;
                    u2[row*SK128 + col] = f2bfb(fmaxf(acc[t][nt][r] + bb, 0.f));
                }
        }
    }

    // ---- GEMM3: scores = sum_col tanh(Ms@aw1 + ab1)*aw2 ----
    {
        s8v af3[2][4];
        #pragma unroll
        for (int t = 0; t < 2; t++)
            #pragma unroll
            for (int ks = 0; ks < 4; ks++)
                af3[t][ks] = *(const s8v*)&u2[(rb + t*16 + l15)*SK128 + ks*32 + quad*8];
        f4v acc[2][2];
        #pragma unroll
        for (int t = 0; t < 2; t++)
            #pragma unroll
            for (int nt = 0; nt < 2; nt++) acc[t][nt] = (f4v){0.f,0.f,0.f,0.f};
        #pragma unroll
        for (int nt = 0; nt < 2; nt++) {
            #pragma unroll
            for (int ks = 0; ks < 4; ks++) {
                s8v bf_ = *(const s8v*)&gaw1T[(size_t)(nt*16 + l15)*SK128 + ks*32 + quad*8];
                acc[0][nt] = MFMA16(af3[0][ks], bf_, acc[0][nt]);
                acc[1][nt] = MFMA16(af3[1][ks], bf_, acc[1][nt]);
            }
        }
        #pragma unroll
        for (int t = 0; t < 2; t++)
            #pragma unroll
            for (int r = 0; r < 4; r++) {
                float s = 0.f;
                #pragma unroll
                for (int nt = 0; nt < 2; nt++) {
                    int col = nt*16 + l15;
                    s += fast_tanh(acc[t][nt][r] + LD<DT>(ab1, col)) * LD<DT>(aw2, col);
                }
                s += __shfl_xor(s, 1);
                s += __shfl_xor(s, 2);
                s += __shfl_xor(s, 4);
                s += __shfl_xor(s, 8);
                if (l15 == 0) ssc[wv][t][quad*4 + r] = s;   // wave-private
            }
    }

    // ---- softmax(16) + aggregate (wave-private, lgkm-ordered) ----
    #pragma unroll
    for (int t = 0; t < 2; t++) {
        float sc[KNN];
        #pragma unroll
        for (int j = 0; j < KNN; j++) sc[j] = ssc[wv][t][j];
        float mx = sc[0];
        #pragma unroll
        for (int j = 1; j < KNN; j++) mx = fmaxf(mx, sc[j]);
        float den = 0.f;
        #pragma unroll
        for (int j = 0; j < KNN; j++) { sc[j] = __expf(sc[j] - mx); den += sc[j]; }
        float inv = 1.f / den;
        float a0 = 0.f, a1 = 0.f;
        #pragma unroll
        for (int j = 0; j < KNN; j++) {
            unsigned v = *(const unsigned*)&u2[(rb + t*16 + j)*SK128 + 2*lane];
            float w = sc[j] * inv;
            a0 += w * bfb2f((unsigned short)(v & 0xFFFFu));
            a1 += w * bfb2f((unsigned short)(v >> 16));
        }
        int mm = m0 + t;
        if (mm < M) {
            if (DT) {
                unsigned pk = (unsigned)f2bfb(a0) | ((unsigned)f2bfb(a1) << 16);
                *(unsigned*)((bf16*)out + (size_t)mm*H2 + 2*lane) = pk;
            } else {
                ST<0>(out, (size_t)mm*H2 + 2*lane, a0);
                ST<0>(out, (size_t)mm*H2 + 2*lane + 1, a1);
            }
            if (lane == 0) {
                ST<DT>(out, (size_t)M*128 + mm*3 + 0, p4v[t][0]);
                ST<DT>(out, (size_t)M*128 + mm*3 + 1, p4v[t][1]);
                ST<DT>(out, (size_t)M*128 + mm*3 + 2, p4v[t][2]);
                ST<DT>(out, (size_t)M*131 + mm, (float)batch[idxarr[mcl[t]]]);
                ST<DT>(out, (size_t)M*132 + mm, p4v[t][3]);
            }
        }
    }
}

// ---------------- post: MFMA, 32 targets/block ----------------
template<int DT> __global__ __launch_bounds__(256) void post_mfma(
    const int* __restrict__ flag,
    const unsigned short* __restrict__ expwT, const unsigned short* __restrict__ d1pwT,
    const unsigned short* __restrict__ d2pwT, const unsigned short* __restrict__ pjwT,
    const float4* __restrict__ C1, const float2* __restrict__ C2,
    const float2* __restrict__ C3, const float2* __restrict__ C4,
    void* __restrict__ out, int M)
{
    if (*flag != DT) return;
    __shared__ __align__(16) unsigned short zs[32*SK512];
    __shared__ __align__(16) unsigned short a0[32*SK128];
    const int tid = threadIdx.x;
    const int m0 = blockIdx.x * 32;

    {
        int r = tid >> 3;
        int c0 = (tid & 7) * 16;
        int mm = m0 + r;
        for (int c = c0; c < c0+16; c++) {
            float v = (mm < M) ? LD<DT>(out, (size_t)mm*RNN + c) : 0.f;
            a0[r*SK128 + c] = f2bfb(v);
        }
        if ((tid & 7) == 7) for (int c = RNN; c < SK128; c++) a0[r*SK128 + c] = 0;
    }
    __syncthreads();

    const int wv = tid >> 6, lane = tid & 63, quad = lane >> 4, l15 = lane & 15;
    const int nbase = wv * 128;

    f4v acc[2][8];

    // exp GEMM
    #pragma unroll
    for (int mt = 0; mt < 2; mt++)
        #pragma unroll
        for (int nt = 0; nt < 8; nt++) acc[mt][nt] = (f4v){0.f,0.f,0.f,0.f};
    #pragma unroll
    for (int ks = 0; ks < 4; ks++) {
        s8v af0 = *(const s8v*)&a0[(l15)*SK128 + ks*32 + quad*8];
        s8v af1 = *(const s8v*)&a0[(16+l15)*SK128 + ks*32 + quad*8];
        #pragma unroll
        for (int nt = 0; nt < 8; nt++) {
            s8v bf_ = *(const s8v*)&expwT[(size_t)(nbase + nt*16 + l15)*SK128 + ks*32 + quad*8];
            acc[0][nt] = MFMA16(af0, bf_, acc[0][nt]);
            acc[1][nt] = MFMA16(af1, bf_, acc[1][nt]);
        }
    }
    #pragma unroll
    for (int nt = 0; nt < 8; nt++) {
        int col = nbase + nt*16 + l15;
        float4 cf = C1[col];
        #pragma unroll
        for (int mt = 0; mt < 2; mt++)
            #pragma unroll
            for (int r = 0; r < 4; r++) {
                int row = mt*16 + quad*4 + r;
                float u = fmaxf(cf.x*acc[mt][nt][r] + cf.y, 0.f);
                float d = fmaxf(cf.z*u + cf.w, 0.f);
                zs[row*SK512 + col] = f2bfb(d);
            }
    }
    __syncthreads();

    // ds1 pw GEMM
    #pragma unroll
    for (int mt = 0; mt < 2; mt++)
        #pragma unroll
        for (int nt = 0; nt < 8; nt++) acc[mt][nt] = (f4v){0.f,0.f,0.f,0.f};
    for (int ks = 0; ks < 16; ks++) {
        s8v af0 = *(const s8v*)&zs[(l15)*SK512 + ks*32 + quad*8];
        s8v af1 = *(const s8v*)&zs[(16+l15)*SK512 + ks*32 + quad*8];
        #pragma unroll
        for (int nt = 0; nt < 8; nt++) {
            s8v bf_ = *(const s8v*)&d1pwT[(size_t)(nbase + nt*16 + l15)*SK512 + ks*32 + quad*8];
            acc[0][nt] = MFMA16(af0, bf_, acc[0][nt]);
            acc[1][nt] = MFMA16(af1, bf_, acc[1][nt]);
        }
    }
    __syncthreads();
    #pragma unroll
    for (int nt = 0; nt < 8; nt++) {
        int col = nbase + nt*16 + l15;
        float2 cf = C2[col];
        #pragma unroll
        for (int mt = 0; mt < 2; mt++)
            #pragma unroll
            for (int r = 0; r < 4; r++) {
                int row = mt*16 + quad*4 + r;
                zs[row*SK512 + col] = f2bfb(fmaxf(cf.x*acc[mt][nt][r] + cf.y, 0.f));
            }
    }
    __syncthreads();

    // ds2 pw GEMM
    #pragma unroll
    for (int mt = 0; mt < 2; mt++)
        #pragma unroll
        for (int nt = 0; nt < 8; nt++) acc[mt][nt] = (f4v){0.f,0.f,0.f,0.f};
    for (int ks = 0; ks < 16; ks++) {
        s8v af0 = *(const s8v*)&zs[(l15)*SK512 + ks*32 + quad*8];
        s8v af1 = *(const s8v*)&zs[(16+l15)*SK512 + ks*32 + quad*8];
        #pragma unroll
        for (int nt = 0; nt < 8; nt++) {
            s8v bf_ = *(const s8v*)&d2pwT[(size_t)(nbase + nt*16 + l15)*SK512 + ks*32 + quad*8];
            acc[0][nt] = MFMA16(af0, bf_, acc[0][nt]);
            acc[1][nt] = MFMA16(af1, bf_, acc[1][nt]);
        }
    }
    __syncthreads();
    #pragma unroll
    for (int nt = 0; nt < 8; nt++) {
        int col = nbase + nt*16 + l15;
        float2 cf = C3[col];
        #pragma unroll
        for (int mt = 0; mt < 2; mt++)
            #pragma unroll
            for (int r = 0; r < 4; r++) {
                int row = mt*16 + quad*4 + r;
                zs[row*SK512 + col] = f2bfb(cf.x*acc[mt][nt][r] + cf.y);
            }
    }
    __syncthreads();

    // proj GEMM + residual
    {
        f4v pacc[2][2];
        #pragma unroll
        for (int mt = 0; mt < 2; mt++)
            #pragma unroll
            for (int nt = 0; nt < 2; nt++) pacc[mt][nt] = (f4v){0.f,0.f,0.f,0.f};
        for (int ks = 0; ks < 16; ks++) {
            s8v af0 = *(const s8v*)&zs[(l15)*SK512 + ks*32 + quad*8];
            s8v af1 = *(const s8v*)&zs[(16+l15)*SK512 + ks*32 + quad*8];
            #pragma unroll
            for (int nt = 0; nt < 2; nt++) {
                s8v bf_ = *(const s8v*)&pjwT[(size_t)(wv*32 + nt*16 + l15)*SK512 + ks*32 + quad*8];
                pacc[0][nt] = MFMA16(af0, bf_, pacc[0][nt]);
                pacc[1][nt] = MFMA16(af1, bf_, pacc[1][nt]);
            }
        }
        #pragma unroll
        for (int nt = 0; nt < 2; nt++) {
            int col = wv*32 + nt*16 + l15;
            float2 cf = C4[col];
            #pragma unroll
            for (int mt = 0; mt < 2; mt++)
                #pragma unroll
                for (int r = 0; r < 4; r++) {
                    int row = mt*16 + quad*4 + r;
                    int mm = m0 + row;
                    if (mm < M) {
                        float agv = bfb2f(a0[row*SK128 + col]);
                        float o = fmaxf(cf.x*pacc[mt][nt][r] + cf.y + agv, 0.f);
                        ST<DT>(out, (size_t)mm*RNN + col, o);
                    }
                }
        }
    }
}

extern "C" void kernel_launch(void* const* d_in, const int* in_sizes, int n_in,
                              void* d_out, int out_size, void* d_ws, size_t ws_size,
                              hipStream_t stream)
{
    const void* x    = d_in[0];
    const void* pos  = d_in[1];
    const void* refl = d_in[2];
    const void* gum  = d_in[3];
    const void* gw1  = d_in[4];
    const void* gb1  = d_in[5];
    const void* gw2  = d_in[6];
    const void* gb2  = d_in[7];
    const void* gwg  = d_in[8];
    const void* gbg  = d_in[9];
    const void* lw1  = d_in[10];
    const void* lb1  = d_in[11];
    const void* lw2  = d_in[12];
    const void* lb2  = d_in[13];
    const void* aw1  = d_in[14];
    const void* ab1  = d_in[15];
    const void* aw2  = d_in[16];
    const void* expw = d_in[17];
    const void* expb = d_in[18];
    const void* expbn= d_in[19];
    const void* d1dw = d_in[20];
    const void* d1bn1= d_in[21];
    const void* d1pw = d_in[22];
    const void* d1pb = d_in[23];
    const void* d1bn2= d_in[24];
    const void* bbn1 = d_in[25];
    const void* d2dw = d_in[26];
    const void* d2bn1= d_in[27];
    const void* d2pw = d_in[28];
    const void* d2pb = d_in[29];
    const void* d2bn2= d_in[30];
    const void* bbn2 = d_in[31];
    const void* pjw  = d_in[32];
    const void* pjb  = d_in[33];
    const void* pjbn = d_in[34];
    const int* batch = (const int*)d_in[35];
    const int* idxp  = (const int*)d_in[36];
    const int* eidx  = (const int*)d_in[37];

    const int N = in_sizes[2];
    const int M = in_sizes[36];
    const int NPC = N / B_GR;
    const int CPB = (NPC + 255) / 256;

    // ws layout (bytes)
    char* wsb = (char*)d_ws;
    int*  flag   = (int*)wsb;
    int*  pooled = (int*)(wsb + 16);
    float* y1    = (float*)(wsb + 2304);
    unsigned short* w1T   = (unsigned short*)(wsb + 2368);
    unsigned short* w2T   = w1T + W1T_E;
    unsigned short* aw1T  = w2T + W2T_E;
    unsigned short* expwT = aw1T + AW1T_E;
    unsigned short* d1pwT = expwT + EXPT_E;
    unsigned short* d2pwT = d1pwT + D1T_E;
    unsigned short* pjwT  = d2pwT + D2T_E;
    unsigned short* gw2gT = pjwT + PJT_E;
    float4* C1 = (float4*)(gw2gT + GW2T_E + 8);
    float2* C2 = (float2*)(C1 + E4);
    float2* C3 = C2 + E4;
    float2* C4 = C3 + E4;

    prep_kernel<<<1, 256, 0, stream>>>(pos, flag, pooled);

    trans_kernel<0><<<512, 256, 0, stream>>>(flag, lw1, lw2, aw1, expw, d1pw, d2pw, pjw, gw2,
                                             w1T, w2T, aw1T, expwT, d1pwT, d2pwT, pjwT, gw2gT);
    trans_kernel<1><<<512, 256, 0, stream>>>(flag, lw1, lw2, aw1, expw, d1pw, d2pw, pjw, gw2,
                                             w1T, w2T, aw1T, expwT, d1pwT, d2pwT, pjwT, gw2gT);

    coef_kernel<0><<<2, 256, 0, stream>>>(flag, expb, expbn, d1dw, d1bn1, d1pb, d1bn2, bbn1,
                                          d2dw, d2bn1, d2pb, d2bn2, bbn2, pjb, pjbn,
                                          C1, C2, C3, C4);
    coef_kernel<1><<<2, 256, 0, stream>>>(flag, expb, expbn, d1dw, d1bn1, d1pb, d1bn2, bbn1,
                                          d2dw, d2bn1, d2pb, d2bn2, bbn2, pjb, pjbn,
                                          C1, C2, C3, C4);

    gate_mfma<0><<<B_GR*CPB, 256, 0, stream>>>(flag, pos, refl, gw1, gb1, gb2, gw2gT, pooled, NPC, CPB);
    gate_mfma<1><<<B_GR*CPB, 256, 0, stream>>>(flag, pos, refl, gw1, gb1, gb2, gw2gT, pooled, NPC, CPB);

    gate2_kernel<0><<<1, 64, 0, stream>>>(flag, pooled, gwg, gbg, gum, y1);
    gate2_kernel<1><<<1, 64, 0, stream>>>(flag, pooled, gwg, gbg, gum, y1);

    const int EB = (M + 7) / 8;
    edge_mfma<0><<<EB, 256, 0, stream>>>(flag, x, pos, refl, y1, batch, idxp, eidx,
                                         lb1, lb2, ab1, aw2, w1T, w2T, aw1T, d_out, M);
    edge_mfma<1><<<EB, 256, 0, stream>>>(flag, x, pos, refl, y1, batch, idxp, eidx,
                                         lb1, lb2, ab1, aw2, w1T, w2T, aw1T, d_out, M);

    const int PB = (M + 31) / 32;
    post_mfma<0><<<PB, 256, 0, stream>>>(flag, expwT, d1pwT, d2pwT, pjwT, C1, C2, C3, C4, d_out, M);
    post_mfma<1><<<PB, 256, 0, stream>>>(flag, expwT, d1pwT, d2pwT, pjwT, C1, C2, C3, C4, d_out, M);
}

// Round 8
// 460.521 us; speedup vs baseline: 1.2178x; 1.0270x over previous
//
#include <hip/hip_runtime.h>
#include <hip/hip_bf16.h>

typedef __hip_bfloat16 bf16;

#define B_GR 8
#define IN_CH 64
#define H1 68
#define H2 128
#define ATTN 32
#define E4 512
#define RNN 128
#define KNN 16
#define EPSV 1e-5f

typedef __attribute__((ext_vector_type(8))) short s8v;
typedef __attribute__((ext_vector_type(4))) float f4v;
#define MFMA16(a,b,c) __builtin_amdgcn_mfma_f32_16x16x32_bf16(a,b,c,0,0,0)

// strides (elements) — +8 pad keeps 16B alignment, breaks pow2 banks
#define SK96 104
#define SK128 136
#define SK512 520

template<int DT> __device__ __forceinline__ float LD(const void* p, size_t i) {
    if (DT) return __bfloat162float(((const bf16*)p)[i]);
    return ((const float*)p)[i];
}
template<int DT> __device__ __forceinline__ void ST(void* p, size_t i, float v) {
    if (DT) ((bf16*)p)[i] = __float2bfloat16(v);
    else    ((float*)p)[i] = v;
}
__device__ __forceinline__ unsigned short f2bfb(float f) {
    unsigned u = __float_as_uint(f);
    unsigned r = (u + 0x7FFFu + ((u >> 16) & 1u)) >> 16;
    return (unsigned short)r;
}
__device__ __forceinline__ float bfb2f(unsigned short u) {
    return __uint_as_float(((unsigned)u) << 16);
}
__device__ __forceinline__ float fast_tanh(float x) {
    x = fminf(fmaxf(x, -12.f), 12.f);
    float e = __expf(2.f * x);
    return (e - 1.f) / (e + 1.f);
}

// ---------------- prep: dtype detect + zero pooled ----------------
__global__ void prep_kernel(const void* pos, int* flag, int* pooled) {
    const int tid = threadIdx.x;
    for (int i = tid; i < B_GR*H1; i += 256) pooled[i] = 0;
    if (tid == 0) {
        const unsigned* w = (const unsigned*)pos;
        int ok = 1;
        #pragma unroll 8
        for (int i = 0; i < 256; i++) {
            float f = __uint_as_float((w[i] & 0xFFFFu) << 16);
            if (!(f >= -0.01f && f <= 10.05f)) ok = 0;
        }
        *flag = ok;
    }
}

// ---------------- transpose+convert weights into ws (bf16 bits) ----------------
#define W1T_E (128*SK96)
#define W2T_E (128*SK128)
#define AW1T_E (32*SK128)
#define EXPT_E (512*SK128)
#define D1T_E (512*SK512)
#define D2T_E (512*SK512)
#define PJT_E (128*SK512)
#define GW2T_E (80*SK96)
template<int DT> __global__ __launch_bounds__(256) void trans_kernel(
    const int* __restrict__ flag,
    const void* __restrict__ w1, const void* __restrict__ w2, const void* __restrict__ aw1,
    const void* __restrict__ expw, const void* __restrict__ d1pw,
    const void* __restrict__ d2pw, const void* __restrict__ pjw,
    const void* __restrict__ gw2,
    unsigned short* __restrict__ w1T, unsigned short* __restrict__ w2T,
    unsigned short* __restrict__ aw1T, unsigned short* __restrict__ expwT,
    unsigned short* __restrict__ d1pwT, unsigned short* __restrict__ d2pwT,
    unsigned short* __restrict__ pjwT, unsigned short* __restrict__ gw2gT)
{
    if (*flag != DT) return;
    const int T0 = W1T_E, T1 = T0+W2T_E, T2 = T1+AW1T_E, T3 = T2+EXPT_E,
              T4 = T3+D1T_E, T5 = T4+D2T_E, T6 = T5+PJT_E, T7 = T6+GW2T_E;
    for (int i = blockIdx.x*256 + threadIdx.x; i < T7; i += gridDim.x*256) {
        if (i < T0) {
            int n = i / SK96, k = i - n*SK96;
            w1T[i] = (k < H1) ? f2bfb(LD<DT>(w1, (size_t)k*H2 + n)) : 0;
        } else if (i < T1) {
            int j = i - T0; int n = j / SK128, k = j - n*SK128;
            w2T[j] = (k < H2) ? f2bfb(LD<DT>(w2, (size_t)k*H2 + n)) : 0;
        } else if (i < T2) {
            int j = i - T1; int n = j / SK128, k = j - n*SK128;
            aw1T[j] = (k < H2) ? f2bfb(LD<DT>(aw1, (size_t)k*ATTN + n)) : 0;
        } else if (i < T3) {
            int j = i - T2; int n = j / SK128, k = j - n*SK128;
            expwT[j] = (k < RNN) ? f2bfb(LD<DT>(expw, (size_t)k*E4 + n)) : 0;
        } else if (i < T4) {
            int j = i - T3; int n = j / SK512, k = j - n*SK512;
            d1pwT[j] = (k < E4) ? f2bfb(LD<DT>(d1pw, (size_t)k*E4 + n)) : 0;
        } else if (i < T5) {
            int j = i - T4; int n = j / SK512, k = j - n*SK512;
            d2pwT[j] = (k < E4) ? f2bfb(LD<DT>(d2pw, (size_t)k*E4 + n)) : 0;
        } else if (i < T6) {
            int j = i - T5; int n = j / SK512, k = j - n*SK512;
            pjwT[j] = (k < E4) ? f2bfb(LD<DT>(pjw, (size_t)k*RNN + n)) : 0;
        } else {
            int j = i - T6; int n = j / SK96, k = j - n*SK96;
            gw2gT[j] = (k < H1 && n < H1) ? f2bfb(LD<DT>(gw2, (size_t)k*H1 + n)) : 0;
        }
    }
}

// ---------------- folded per-column affine coefficients for post ----------------
template<int DT> __global__ void coef_kernel(
    const int* __restrict__ flag,
    const void* __restrict__ expb, const void* __restrict__ expbn,
    const void* __restrict__ d1dw, const void* __restrict__ d1bn1,
    const void* __restrict__ d1pb, const void* __restrict__ d1bn2, const void* __restrict__ bbn1,
    const void* __restrict__ d2dw, const void* __restrict__ d2bn1,
    const void* __restrict__ d2pb, const void* __restrict__ d2bn2, const void* __restrict__ bbn2,
    const void* __restrict__ pjb, const void* __restrict__ pjbn,
    float4* __restrict__ C1, float2* __restrict__ C2, float2* __restrict__ C3,
    float2* __restrict__ C4)
{
    if (*flag != DT) return;
    int c = blockIdx.x*256 + threadIdx.x;
    if (c < E4) {
        float a_e = LD<DT>(expbn,c) * rsqrtf(LD<DT>(expbn,3*E4+c)+EPSV);
        float t0  = a_e*(LD<DT>(expb,c) - LD<DT>(expbn,2*E4+c)) + LD<DT>(expbn,E4+c);
        float a1 = LD<DT>(d1bn1,c) * rsqrtf(LD<DT>(d1bn1,3*E4+c)+EPSV);
        float s1 = a1 * LD<DT>(d1dw,c);
        float t1 = a1*(LD<DT>(d1dw,E4+c) - LD<DT>(d1bn1,2*E4+c)) + LD<DT>(d1bn1,E4+c);
        C1[c] = make_float4(a_e, t0, s1, t1);
        float a2 = LD<DT>(d1bn2,c) * rsqrtf(LD<DT>(d1bn2,3*E4+c)+EPSV);
        float t2 = a2*(LD<DT>(d1pb,c) - LD<DT>(d1bn2,2*E4+c)) + LD<DT>(d1bn2,E4+c);
        float a3 = LD<DT>(bbn1,c) * rsqrtf(LD<DT>(bbn1,3*E4+c)+EPSV);
        float S2 = a3*a2;
        float T2 = a3*(t2 - LD<DT>(bbn1,2*E4+c)) + LD<DT>(bbn1,E4+c);
        float a4 = LD<DT>(d2bn1,c) * rsqrtf(LD<DT>(d2bn1,3*E4+c)+EPSV);
        float sdw = a4 * LD<DT>(d2dw,c);
        float tdw = a4*(LD<DT>(d2dw,E4+c) - LD<DT>(d2bn1,2*E4+c)) + LD<DT>(d2bn1,E4+c);
        C2[c] = make_float2(sdw*S2, sdw*T2 + tdw);
        float a5 = LD<DT>(d2bn2,c) * rsqrtf(LD<DT>(d2bn2,3*E4+c)+EPSV);
        float t5 = a5*(LD<DT>(d2pb,c) - LD<DT>(d2bn2,2*E4+c)) + LD<DT>(d2bn2,E4+c);
        float a6 = LD<DT>(bbn2,c) * rsqrtf(LD<DT>(bbn2,3*E4+c)+EPSV);
        C3[c] = make_float2(a6*a5, a6*(t5 - LD<DT>(bbn2,2*E4+c)) + LD<DT>(bbn2,E4+c));
    }
    if (c < RNN) {
        float ap = LD<DT>(pjbn,c) * rsqrtf(LD<DT>(pjbn,3*RNN+c)+EPSV);
        C4[c] = make_float2(ap, ap*(LD<DT>(pjb,c) - LD<DT>(pjbn,2*RNN+c)) + LD<DT>(pjbn,RNN+c));
    }
}

// ---------------- gate: layer1 VALU + layer2 MFMA + segment max ----------------
template<int DT> __global__ __launch_bounds__(256) void gate_mfma(
    const int* __restrict__ flag,
    const void* __restrict__ pos, const void* __restrict__ refl,
    const void* __restrict__ w1, const void* __restrict__ b1, const void* __restrict__ b2g,
    const unsigned short* __restrict__ gw2gT,
    int* __restrict__ pooled, int NPC, int CPB)
{
    if (*flag != DT) return;
    __shared__ __align__(16) unsigned short hs[256*SK96];
    __shared__ float w1s[4*H1], b1s[H1], b2s[H1];
    const int tid = threadIdx.x;
    for (int i = tid; i < 4*H1; i += 256) w1s[i] = LD<DT>(w1, i);
    if (tid < H1) { b1s[tid] = LD<DT>(b1, tid); b2s[tid] = LD<DT>(b2g, tid); }
    __syncthreads();

    const int bb = blockIdx.x / CPB;
    const int cc = blockIdx.x % CPB;
    const int base = bb*NPC + cc*256;
    const int limit = NPC - cc*256;
    const int p = base + ((tid < limit) ? tid : 0);

    {
        float f0 = LD<DT>(pos, (size_t)p*3+0), f1 = LD<DT>(pos, (size_t)p*3+1);
        float f2 = LD<DT>(pos, (size_t)p*3+2), f3 = LD<DT>(refl, p);
        float h[H1];
        #pragma unroll
        for (int j = 0; j < H1; j++)
            h[j] = fmaxf(b1s[j] + f0*w1s[j] + f1*w1s[H1+j] + f2*w1s[2*H1+j] + f3*w1s[3*H1+j], 0.f);
        #pragma unroll
        for (int j = 0; j < H1; j += 2) {
            unsigned v = (unsigned)f2bfb(h[j]) | ((unsigned)f2bfb(h[j+1]) << 16);
            *(unsigned*)&hs[tid*SK96 + j] = v;
        }
        #pragma unroll
        for (int j = H1; j < 96; j += 2) *(unsigned*)&hs[tid*SK96 + j] = 0;
    }
    __syncthreads();

    const int wv = tid >> 6, lane = tid & 63, quad = lane >> 4, l15 = lane & 15;
    f4v acc[4][5];
    #pragma unroll
    for (int mt = 0; mt < 4; mt++)
        #pragma unroll
        for (int nt = 0; nt < 5; nt++) acc[mt][nt] = (f4v){0.f,0.f,0.f,0.f};
    s8v af[4][3];
    #pragma unroll
    for (int mt = 0; mt < 4; mt++)
        #pragma unroll
        for (int ks = 0; ks < 3; ks++)
            af[mt][ks] = *(const s8v*)&hs[(wv*64 + mt*16 + l15)*SK96 + ks*32 + quad*8];
    #pragma unroll
    for (int nt = 0; nt < 5; nt++) {
        #pragma unroll
        for (int ks = 0; ks < 3; ks++) {
            s8v bf_ = *(const s8v*)&gw2gT[(size_t)(nt*16 + l15)*SK96 + ks*32 + quad*8];
            #pragma unroll
            for (int mt = 0; mt < 4; mt++) acc[mt][nt] = MFMA16(af[mt][ks], bf_, acc[mt][nt]);
        }
    }
    #pragma unroll
    for (int nt = 0; nt < 5; nt++) {
        int col = nt*16 + l15;
        float v = acc[0][nt][0];
        #pragma unroll
        for (int mt = 0; mt < 4; mt++)
            #pragma unroll
            for (int r = 0; r < 4; r++) v = fmaxf(v, acc[mt][nt][r]);
        v = fmaxf(v, __shfl_xor(v, 16));
        v = fmaxf(v, __shfl_xor(v, 32));
        if (quad == 0 && col < H1) {
            float o = fmaxf(v + b2s[col], 0.f);
            atomicMax(&pooled[bb*H1 + col], __float_as_int(o));
        }
    }
}

// ---------------- gate logits + gumbel softmax -> y1 ----------------
template<int DT> __global__ void gate2_kernel(
    const int* __restrict__ flag, const int* __restrict__ pooled,
    const void* __restrict__ wg, const void* __restrict__ bg,
    const void* __restrict__ gum, float* __restrict__ y1)
{
    if (*flag != DT) return;
    __shared__ float lg[B_GR][2];
    const int t = threadIdx.x;
    if (t < B_GR*2) {
        int b = t >> 1, g = t & 1;
        float a = LD<DT>(bg, g) + LD<DT>(gum, b*2+g);
        for (int c = 0; c < H1; c++) a += __int_as_float(pooled[b*H1+c]) * LD<DT>(wg, c*2+g);
        lg[b][g] = a;
    }
    __syncthreads();
    if (t < B_GR) {
        float l0 = lg[t][0], l1 = lg[t][1];
        float m = fmaxf(l0, l1);
        float e0 = __expf(l0-m), e1 = __expf(l1-m);
        y1[t] = e1 / (e0 + e1);
    }
}

// ---------------- edge: barrier-free, wave-private (2 targets per wave) ----------------
template<int DT> __global__ __launch_bounds__(256) void edge_mfma(
    const int* __restrict__ flag,
    const void* __restrict__ x, const void* __restrict__ pos,
    const void* __restrict__ refl, const float* __restrict__ y1,
    const int* __restrict__ batch,
    const int* __restrict__ idxarr, const int* __restrict__ esrc,
    const void* __restrict__ b1, const void* __restrict__ b2,
    const void* __restrict__ ab1, const void* __restrict__ aw2,
    const unsigned short* __restrict__ gw1T, const unsigned short* __restrict__ gw2T,
    const unsigned short* __restrict__ gaw1T,
    void* __restrict__ out, int M)
{
    if (*flag != DT) return;
    __shared__ __align__(16) unsigned short u2[128*SK128];   // wave-private strips
    __shared__ float ssc[4][2][16];

    const int tid = threadIdx.x;
    const int wv = tid >> 6, lane = tid & 63, quad = lane >> 4, l15 = lane & 15;
    const int m0 = blockIdx.x * 8 + wv * 2;
    const int rb = wv * 32;

    s8v af[2][3];
    int mcl[2];
    float p4v[2][4];
    #pragma unroll
    for (int t = 0; t < 2; t++) {
        int mm = m0 + t; if (mm >= M) mm = M - 1;
        mcl[t] = mm;
        int t_idx = idxarr[mm];
        p4v[t][0] = LD<DT>(pos, (size_t)t_idx*3 + 0);
        p4v[t][1] = LD<DT>(pos, (size_t)t_idx*3 + 1);
        p4v[t][2] = LD<DT>(pos, (size_t)t_idx*3 + 2);
        p4v[t][3] = y1[batch[t_idx]] * LD<DT>(refl, t_idx);
        int s = esrc[mm*KNN + l15];
        if (DT) {
            const unsigned short* xs = (const unsigned short*)x + (size_t)s*IN_CH;
            af[t][0] = *(const s8v*)(xs + quad*8);
            af[t][1] = *(const s8v*)(xs + 32 + quad*8);
        } else {
            unsigned short tmp0[8], tmp1[8];
            #pragma unroll
            for (int e = 0; e < 8; e++) {
                tmp0[e] = f2bfb(LD<0>(x, (size_t)s*IN_CH + quad*8 + e));
                tmp1[e] = f2bfb(LD<0>(x, (size_t)s*IN_CH + 32 + quad*8 + e));
            }
            af[t][0] = *(const s8v*)tmp0;
            af[t][1] = *(const s8v*)tmp1;
        }
        s8v a2 = (s8v){0,0,0,0,0,0,0,0};
        if (quad == 0) {
            a2[0] = (short)f2bfb(LD<DT>(pos, (size_t)s*3 + 0) - p4v[t][0]);
            a2[1] = (short)f2bfb(LD<DT>(pos, (size_t)s*3 + 1) - p4v[t][1]);
            a2[2] = (short)f2bfb(LD<DT>(pos, (size_t)s*3 + 2) - p4v[t][2]);
            a2[3] = (short)f2bfb(y1[batch[s]] * LD<DT>(refl, s) - p4v[t][3]);
        }
        af[t][2] = a2;
    }

    // GEMM1
    {
        f4v acc[2][8];
        #pragma unroll
        for (int t = 0; t < 2; t++)
            #pragma unroll
            for (int nt = 0; nt < 8; nt++) acc[t][nt] = (f4v){0.f,0.f,0.f,0.f};
        #pragma unroll
        for (int nt = 0; nt < 8; nt++) {
            #pragma unroll
            for (int ks = 0; ks < 3; ks++) {
                s8v bf_ = *(const s8v*)&gw1T[(size_t)(nt*16 + l15)*SK96 + ks*32 + quad*8];
                acc[0][nt] = MFMA16(af[0][ks], bf_, acc[0][nt]);
                acc[1][nt] = MFMA16(af[1][ks], bf_, acc[1][nt]);
            }
        }
        #pragma unroll
        for (int nt = 0; nt < 8; nt++) {
            int col = nt*16 + l15;
            float bb = LD<DT>(b1, col);
            #pragma unroll
            for (int t = 0; t < 2; t++)
                #pragma unroll
                for (int r = 0; r < 4; r++) {
                    int row = rb + t*16 + quad*4 + r;
                    u2[row*SK128 + col] = f2bfb(fmaxf(acc[t][nt][r] + bb, 0.f));
                }
        }
    }

    // GEMM2
    {
        s8v af2[2][4];
        #pragma unroll
        for (int t = 0; t < 2; t++)
            #pragma unroll
            for (int ks = 0; ks < 4; ks++)
                af2[t][ks] = *(const s8v*)&u2[(rb + t*16 + l15)*SK128 + ks*32 + quad*8];
        f4v acc[2][8];
        #pragma unroll
        for (int t = 0; t < 2; t++)
            #pragma unroll
            for (int nt = 0; nt < 8; nt++) acc[t][nt] = (f4v){0.f,0.f,0.f,0.f};
        #pragma unroll
        for (int nt = 0; nt < 8; nt++) {
            #pragma unroll
            for (int ks = 0; ks < 4; ks++) {
                s8v bf_ = *(const s8v*)&gw2T[(size_t)(nt*16 + l15)*SK128 + ks*32 + quad*8];
                acc[0][nt] = MFMA16(af2[0][ks], bf_, acc[0][nt]);
                acc[1][nt] = MFMA16(af2[1][ks], bf_, acc[1][nt]);
            }
        }
        #pragma unroll
        for (int nt = 0; nt < 8; nt++) {
            int col = nt*16 + l15;
            float bb = LD<DT>(b2, col);
            #pragma unroll
            for (int t = 0; t < 2; t++)
                #pragma unroll
                for (int r = 0; r < 4; r++) {
                    int row = rb + t*16 + quad*4 + r;
                    u2[row*SK128 + col] = f2bfb(fmaxf(acc[t][nt][r] + bb, 0.f));
                }
        }
    }

    // GEMM3 + scores
    {
        s8v af3[2][4];
        #pragma unroll
        for (int t = 0; t < 2; t++)
            #pragma unroll
            for (int ks = 0; ks < 4; ks++)
                af3[t][ks] = *(const s8v*)&u2[(rb + t*16 + l15)*SK128 + ks*32 + quad*8];
        f4v acc[2][2];
        #pragma unroll
        for (int t = 0; t < 2; t++)
            #pragma unroll
            for (int nt = 0; nt < 2; nt++) acc[t][nt] = (f4v){0.f,0.f,0.f,0.f};
        #pragma unroll
        for (int nt = 0; nt < 2; nt++) {
            #pragma unroll
            for (int ks = 0; ks < 4; ks++) {
                s8v bf_ = *(const s8v*)&gaw1T[(size_t)(nt*16 + l15)*SK128 + ks*32 + quad*8];
                acc[0][nt] = MFMA16(af3[0][ks], bf_, acc[0][nt]);
                acc[1][nt] = MFMA16(af3[1][ks], bf_, acc[1][nt]);
            }
        }
        #pragma unroll
        for (int t = 0; t < 2; t++)
            #pragma unroll
            for (int r = 0; r < 4; r++) {
                float s = 0.f;
                #pragma unroll
                for (int nt = 0; nt < 2; nt++) {
                    int col = nt*16 + l15;
                    s += fast_tanh(acc[t][nt][r] + LD<DT>(ab1, col)) * LD<DT>(aw2, col);
                }
                s += __shfl_xor(s, 1);
                s += __shfl_xor(s, 2);
                s += __shfl_xor(s, 4);
                s += __shfl_xor(s, 8);
                if (l15 == 0) ssc[wv][t][quad*4 + r] = s;
            }
    }

    // softmax + aggregate
    #pragma unroll
    for (int t = 0; t < 2; t++) {
        float sc[KNN];
        #pragma unroll
        for (int j = 0; j < KNN; j++) sc[j] = ssc[wv][t][j];
        float mx = sc[0];
        #pragma unroll
        for (int j = 1; j < KNN; j++) mx = fmaxf(mx, sc[j]);
        float den = 0.f;
        #pragma unroll
        for (int j = 0; j < KNN; j++) { sc[j] = __expf(sc[j] - mx); den += sc[j]; }
        float inv = 1.f / den;
        float a0 = 0.f, a1 = 0.f;
        #pragma unroll
        for (int j = 0; j < KNN; j++) {
            unsigned v = *(const unsigned*)&u2[(rb + t*16 + j)*SK128 + 2*lane];
            float w = sc[j] * inv;
            a0 += w * bfb2f((unsigned short)(v & 0xFFFFu));
            a1 += w * bfb2f((unsigned short)(v >> 16));
        }
        int mm = m0 + t;
        if (mm < M) {
            if (DT) {
                unsigned pk = (unsigned)f2bfb(a0) | ((unsigned)f2bfb(a1) << 16);
                *(unsigned*)((bf16*)out + (size_t)mm*H2 + 2*lane) = pk;
            } else {
                ST<0>(out, (size_t)mm*H2 + 2*lane, a0);
                ST<0>(out, (size_t)mm*H2 + 2*lane + 1, a1);
            }
            if (lane == 0) {
                ST<DT>(out, (size_t)M*128 + mm*3 + 0, p4v[t][0]);
                ST<DT>(out, (size_t)M*128 + mm*3 + 1, p4v[t][1]);
                ST<DT>(out, (size_t)M*128 + mm*3 + 2, p4v[t][2]);
                ST<DT>(out, (size_t)M*131 + mm, (float)batch[idxarr[mcl[t]]]);
                ST<DT>(out, (size_t)M*132 + mm, p4v[t][3]);
            }
        }
    }
}

// ---------------- post: barrier-free, wave-private (16 targets per wave) ----------------
// block = 128 threads = 2 waves = 32 targets; NO __syncthreads. Each wave owns a
// 16-row LDS strip (16x520 bf16); A-frags held in registers per layer so the
// strip overwrite is WAR-safe; exp A-frags and proj residual read global `out`.
template<int DT> __global__ __launch_bounds__(128) void post_mfma(
    const int* __restrict__ flag,
    const unsigned short* __restrict__ expwT, const unsigned short* __restrict__ d1pwT,
    const unsigned short* __restrict__ d2pwT, const unsigned short* __restrict__ pjwT,
    const float4* __restrict__ C1, const float2* __restrict__ C2,
    const float2* __restrict__ C3, const float2* __restrict__ C4,
    void* __restrict__ out, int M)
{
    if (*flag != DT) return;
    __shared__ __align__(16) unsigned short zs[32*SK512];   // 2 waves x 16 rows = 33.3 KB
    const int tid = threadIdx.x;
    const int wv = tid >> 6, lane = tid & 63, quad = lane >> 4, l15 = lane & 15;
    const int m0w = blockIdx.x * 32 + wv * 16;
    unsigned short* strip = zs + wv * 16 * SK512;

    // ---- exp GEMM: A straight from global out (agg), K=128 ----
    {
        s8v afe[4];
        int mrow = m0w + l15; if (mrow >= M) mrow = M - 1;
        if (DT) {
            const unsigned short* op = (const unsigned short*)out + (size_t)mrow*RNN;
            #pragma unroll
            for (int ks = 0; ks < 4; ks++)
                afe[ks] = *(const s8v*)(op + ks*32 + quad*8);
        } else {
            #pragma unroll
            for (int ks = 0; ks < 4; ks++) {
                unsigned short tmp[8];
                #pragma unroll
                for (int e = 0; e < 8; e++)
                    tmp[e] = f2bfb(LD<0>(out, (size_t)mrow*RNN + ks*32 + quad*8 + e));
                afe[ks] = *(const s8v*)tmp;
            }
        }
        #pragma unroll 4
        for (int nt = 0; nt < 32; nt++) {
            f4v acc = (f4v){0.f,0.f,0.f,0.f};
            #pragma unroll
            for (int ks = 0; ks < 4; ks++) {
                s8v bf_ = *(const s8v*)&expwT[(size_t)(nt*16 + l15)*SK128 + ks*32 + quad*8];
                acc = MFMA16(afe[ks], bf_, acc);
            }
            int col = nt*16 + l15;
            float4 cf = C1[col];
            #pragma unroll
            for (int r = 0; r < 4; r++) {
                float u = fmaxf(cf.x*acc[r] + cf.y, 0.f);
                float d = fmaxf(cf.z*u + cf.w, 0.f);
                strip[(quad*4 + r)*SK512 + col] = f2bfb(d);
            }
        }
    }

    // ---- ds1 pw: K=512, A-frags in registers, strip overwritten in place ----
    {
        s8v af[16];
        #pragma unroll
        for (int ks = 0; ks < 16; ks++)
            af[ks] = *(const s8v*)&strip[l15*SK512 + ks*32 + quad*8];
        #pragma unroll 2
        for (int nt = 0; nt < 32; nt++) {
            f4v acc = (f4v){0.f,0.f,0.f,0.f};
            #pragma unroll
            for (int ks = 0; ks < 16; ks++) {
                s8v bf_ = *(const s8v*)&d1pwT[(size_t)(nt*16 + l15)*SK512 + ks*32 + quad*8];
                acc = MFMA16(af[ks], bf_, acc);
            }
            int col = nt*16 + l15;
            float2 cf = C2[col];
            #pragma unroll
            for (int r = 0; r < 4; r++)
                strip[(quad*4 + r)*SK512 + col] = f2bfb(fmaxf(cf.x*acc[r] + cf.y, 0.f));
        }
    }

    // ---- ds2 pw: same, epilogue C3 (no relu) ----
    {
        s8v af[16];
        #pragma unroll
        for (int ks = 0; ks < 16; ks++)
            af[ks] = *(const s8v*)&strip[l15*SK512 + ks*32 + quad*8];
        #pragma unroll 2
        for (int nt = 0; nt < 32; nt++) {
            f4v acc = (f4v){0.f,0.f,0.f,0.f};
            #pragma unroll
            for (int ks = 0; ks < 16; ks++) {
                s8v bf_ = *(const s8v*)&d2pwT[(size_t)(nt*16 + l15)*SK512 + ks*32 + quad*8];
                acc = MFMA16(af[ks], bf_, acc);
            }
            int col = nt*16 + l15;
            float2 cf = C3[col];
            #pragma unroll
            for (int r = 0; r < 4; r++)
                strip[(quad*4 + r)*SK512 + col] = f2bfb(cf.x*acc[r] + cf.y);
        }
    }

    // ---- proj: N=128; epilogue C4 + residual (re-read agg from out, then overwrite) ----
    {
        s8v af[16];
        #pragma unroll
        for (int ks = 0; ks < 16; ks++)
            af[ks] = *(const s8v*)&strip[l15*SK512 + ks*32 + quad*8];
        #pragma unroll 2
        for (int nt = 0; nt < 8; nt++) {
            f4v acc = (f4v){0.f,0.f,0.f,0.f};
            #pragma unroll
            for (int ks = 0; ks < 16; ks++) {
                s8v bf_ = *(const s8v*)&pjwT[(size_t)(nt*16 + l15)*SK512 + ks*32 + quad*8];
                acc = MFMA16(af[ks], bf_, acc);
            }
            int col = nt*16 + l15;
            float2 cf = C4[col];
            #pragma unroll
            for (int r = 0; r < 4; r++) {
                int mm = m0w + quad*4 + r;
                if (mm < M) {
                    float agv = LD<DT>(out, (size_t)mm*RNN + col);
                    float o = fmaxf(cf.x*acc[r] + cf.y + agv, 0.f);
                    ST<DT>(out, (size_t)mm*RNN + col, o);
                }
            }
        }
    }
}

extern "C" void kernel_launch(void* const* d_in, const int* in_sizes, int n_in,
                              void* d_out, int out_size, void* d_ws, size_t ws_size,
                              hipStream_t stream)
{
    const void* x    = d_in[0];
    const void* pos  = d_in[1];
    const void* refl = d_in[2];
    const void* gum  = d_in[3];
    const void* gw1  = d_in[4];
    const void* gb1  = d_in[5];
    const void* gw2  = d_in[6];
    const void* gb2  = d_in[7];
    const void* gwg  = d_in[8];
    const void* gbg  = d_in[9];
    const void* lw1  = d_in[10];
    const void* lb1  = d_in[11];
    const void* lw2  = d_in[12];
    const void* lb2  = d_in[13];
    const void* aw1  = d_in[14];
    const void* ab1  = d_in[15];
    const void* aw2  = d_in[16];
    const void* expw = d_in[17];
    const void* expb = d_in[18];
    const void* expbn= d_in[19];
    const void* d1dw = d_in[20];
    const void* d1bn1= d_in[21];
    const void* d1pw = d_in[22];
    const void* d1pb = d_in[23];
    const void* d1bn2= d_in[24];
    const void* bbn1 = d_in[25];
    const void* d2dw = d_in[26];
    const void* d2bn1= d_in[27];
    const void* d2pw = d_in[28];
    const void* d2pb = d_in[29];
    const void* d2bn2= d_in[30];
    const void* bbn2 = d_in[31];
    const void* pjw  = d_in[32];
    const void* pjb  = d_in[33];
    const void* pjbn = d_in[34];
    const int* batch = (const int*)d_in[35];
    const int* idxp  = (const int*)d_in[36];
    const int* eidx  = (const int*)d_in[37];

    const int N = in_sizes[2];
    const int M = in_sizes[36];
    const int NPC = N / B_GR;
    const int CPB = (NPC + 255) / 256;

    // ws layout (bytes)
    char* wsb = (char*)d_ws;
    int*  flag   = (int*)wsb;
    int*  pooled = (int*)(wsb + 16);
    float* y1    = (float*)(wsb + 2304);
    unsigned short* w1T   = (unsigned short*)(wsb + 2368);
    unsigned short* w2T   = w1T + W1T_E;
    unsigned short* aw1T  = w2T + W2T_E;
    unsigned short* expwT = aw1T + AW1T_E;
    unsigned short* d1pwT = expwT + EXPT_E;
    unsigned short* d2pwT = d1pwT + D1T_E;
    unsigned short* pjwT  = d2pwT + D2T_E;
    unsigned short* gw2gT = pjwT + PJT_E;
    float4* C1 = (float4*)(gw2gT + GW2T_E + 8);
    float2* C2 = (float2*)(C1 + E4);
    float2* C3 = C2 + E4;
    float2* C4 = C3 + E4;

    prep_kernel<<<1, 256, 0, stream>>>(pos, flag, pooled);

    trans_kernel<0><<<512, 256, 0, stream>>>(flag, lw1, lw2, aw1, expw, d1pw, d2pw, pjw, gw2,
                                             w1T, w2T, aw1T, expwT, d1pwT, d2pwT, pjwT, gw2gT);
    trans_kernel<1><<<512, 256, 0, stream>>>(flag, lw1, lw2, aw1, expw, d1pw, d2pw, pjw, gw2,
                                             w1T, w2T, aw1T, expwT, d1pwT, d2pwT, pjwT, gw2gT);

    coef_kernel<0><<<2, 256, 0, stream>>>(flag, expb, expbn, d1dw, d1bn1, d1pb, d1bn2, bbn1,
                                          d2dw, d2bn1, d2pb, d2bn2, bbn2, pjb, pjbn,
                                          C1, C2, C3, C4);
    coef_kernel<1><<<2, 256, 0, stream>>>(flag, expb, expbn, d1dw, d1bn1, d1pb, d1bn2, bbn1,
                                          d2dw, d2bn1, d2pb, d2bn2, bbn2, pjb, pjbn,
                                          C1, C2, C3, C4);

    gate_mfma<0><<<B_GR*CPB, 256, 0, stream>>>(flag, pos, refl, gw1, gb1, gb2, gw2gT, pooled, NPC, CPB);
    gate_mfma<1><<<B_GR*CPB, 256, 0, stream>>>(flag, pos, refl, gw1, gb1, gb2, gw2gT, pooled, NPC, CPB);

    gate2_kernel<0><<<1, 64, 0, stream>>>(flag, pooled, gwg, gbg, gum, y1);
    gate2_kernel<1><<<1, 64, 0, stream>>>(flag, pooled, gwg, gbg, gum, y1);

    const int EB = (M + 7) / 8;
    edge_mfma<0><<<EB, 256, 0, stream>>>(flag, x, pos, refl, y1, batch, idxp, eidx,
                                         lb1, lb2, ab1, aw2, w1T, w2T, aw1T, d_out, M);
    edge_mfma<1><<<EB, 256, 0, stream>>>(flag, x, pos, refl, y1, batch, idxp, eidx,
                                         lb1, lb2, ab1, aw2, w1T, w2T, aw1T, d_out, M);

    const int PB = (M + 31) / 32;
    post_mfma<0><<<PB, 128, 0, stream>>>(flag, expwT, d1pwT, d2pwT, pjwT, C1, C2, C3, C4, d_out, M);
    post_mfma<1><<<PB, 128, 0, stream>>>(flag, expwT, d1pwT, d2pwT, pjwT, C1, C2, C3, C4, d_out, M);
}